// Round 14
// baseline (35041.742 us; speedup 1.0000x reference)
//
#include <hip/hip_runtime.h>
#include <math.h>

#define BB 64
#define LL 256
#define EE 512
#define HH 1024
#define MM 2048
#define HSZ 64
#define RR 4
#define CIN 768
#define PO 1280
#define OO 1024
#define EPSF 1e-5f
#define NT 512
#define NB_REQ 256
#define MS 36                 // LDS mem row stride in u32 (144 B, 16B-aligned, bank-spread)
#define CSL 512               // rows per chunk block

// ---- d_out layout (float offsets) ----
#define OUT_Y    0
#define OUT_MEM  (BB * LL * OO)
#define OUT_HT   (OUT_MEM + BB * MM * HSZ)
#define OUT_CT   (OUT_HT + BB * HH)

// ---- workspace (float offsets inside ws = dyn_lds after mem region) ----
#define WS_RAW   0
#define WS_SW    512
#define WS_SRD   1024          // 4*512
#define WS_BCG   3072          // 128
#define WS_PHN   3200          // 1024
#define WS_RKN   4224          // 256
#define WS_WKN   4480
#define WS_ERS   4544
#define WS_ADS   4608
#define WS_WSS   4672
#define WS_PART  5120          // 4096 (P3 staging)
#define WS_ROW   5120          // 1280 (P4, different phase)
#define WS_CIROW 6400          // 768
#define WS_GEMM_A  0
#define WS_GEMM_W  2176
#define WS_GEMM_G  10880
#define WS_FLOATS  13056
#define DYN_BYTES ((512*MS + WS_FLOATS) * 4)

struct Params {
  const float *x_emb, *ln_in_g, *ln_in_b, *w_ih, *w_hh, *b_ih, *b_hh;
  const float *ln_c_g, *ln_c_b, *w_rk, *b_rk, *w_wk, *b_wk, *w_ws, *b_ws;
  const float *w_er, *b_er, *w_ad, *b_ad, *ln_rk_g, *ln_rk_b, *ln_wk_g, *ln_wk_b;
  const float *ln_m_g, *ln_m_b, *ln_o_g, *ln_o_b, *w_p, *b_p;
  float *y, *mem, *ht, *ct;
  float *c, *wpart, *rpart, *rvpart;
  unsigned *h16, *ci16, *orow16;
  unsigned short *wih16, *whh16, *wp16, *whd16;
  unsigned *bar;
};

__device__ __forceinline__ float sigm(float x){ return 1.f/(1.f+expf(-x)); }
__device__ __forceinline__ float bl(unsigned u){ return __uint_as_float(u<<16); }
__device__ __forceinline__ float bh(unsigned u){ return __uint_as_float(u & 0xffff0000u); }
__device__ __forceinline__ unsigned pk2(float a, float b){
  unsigned ua = __float_as_uint(a), ub = __float_as_uint(b);
  ua = (ua + 0x7fffu + ((ua>>16)&1u)) >> 16;
  ub = (ub + 0x7fffu + ((ub>>16)&1u)) >> 16;
  return ua | (ub<<16);
}

// agent-scope coherent accessors for CROSS-BLOCK tensors
__device__ __forceinline__ unsigned dloadu(const unsigned* p){
  return __hip_atomic_load(p, __ATOMIC_RELAXED, __HIP_MEMORY_SCOPE_AGENT);
}
__device__ __forceinline__ uint2 dloadu2(const unsigned* p){
  unsigned long long u = __hip_atomic_load((const unsigned long long*)p,
                                           __ATOMIC_RELAXED, __HIP_MEMORY_SCOPE_AGENT);
  uint2 r; r.x = (unsigned)(u & 0xffffffffull); r.y = (unsigned)(u >> 32); return r;
}
__device__ __forceinline__ void dstoreu(unsigned* p, unsigned v){
  __hip_atomic_store(p, v, __ATOMIC_RELAXED, __HIP_MEMORY_SCOPE_AGENT);
}
__device__ __forceinline__ float dloadf(const float* p){
  return __hip_atomic_load(p, __ATOMIC_RELAXED, __HIP_MEMORY_SCOPE_AGENT);
}
__device__ __forceinline__ void dstoref(float* p, float v){
  __hip_atomic_store(p, v, __ATOMIC_RELAXED, __HIP_MEMORY_SCOPE_AGENT);
}

__device__ __forceinline__ void lds_barrier() {
  asm volatile("s_waitcnt lgkmcnt(0)" ::: "memory");
  __builtin_amdgcn_sched_barrier(0);
  __builtin_amdgcn_s_barrier();
  __builtin_amdgcn_sched_barrier(0);
}

// 2-level tree grid barrier: 16 leaves x 16 blocks. Every counter on its own
// 64B line: leaf arrivals bar[16+g*16], root bar[0], releases bar[512+g*16].
// Monotone counters -> no reset race. Requires gridDim.x == 256.
__device__ __forceinline__ void gbar(unsigned* bar, unsigned bnum) {
  __syncthreads();
  if (threadIdx.x == 0) {
    asm volatile("s_waitcnt vmcnt(0)" ::: "memory");
    int g = blockIdx.x & 15;
    unsigned a = __hip_atomic_fetch_add(&bar[16 + g*16], 1u,
                    __ATOMIC_RELAXED, __HIP_MEMORY_SCOPE_AGENT) + 1u;
    if (a == bnum * 16u) {
      unsigned r = __hip_atomic_fetch_add(&bar[0], 1u,
                      __ATOMIC_RELAXED, __HIP_MEMORY_SCOPE_AGENT) + 1u;
      if (r == bnum * 16u) {
        #pragma unroll
        for (int i=0;i<16;++i)
          __hip_atomic_fetch_add(&bar[512 + i*16], 1u,
                                 __ATOMIC_RELAXED, __HIP_MEMORY_SCOPE_AGENT);
      }
    }
    while (__hip_atomic_load(&bar[512 + g*16], __ATOMIC_RELAXED,
                             __HIP_MEMORY_SCOPE_AGENT) < bnum) {
      __builtin_amdgcn_s_sleep(8);
    }
    asm volatile("" ::: "memory");
  }
  __syncthreads();
}

__device__ __forceinline__ float bsum(float v, volatile float* red){
  __syncthreads();
  for (int o=32;o>0;o>>=1) v += __shfl_down(v,o,64);
  int w = threadIdx.x>>6;
  if ((threadIdx.x&63)==0) red[w]=v;
  __syncthreads();
  return red[0]+red[1]+red[2]+red[3]+red[4]+red[5]+red[6]+red[7];
}
__device__ __forceinline__ float bmax(float v, volatile float* red){
  __syncthreads();
  for (int o=32;o>0;o>>=1) v = fmaxf(v,__shfl_down(v,o,64));
  int w = threadIdx.x>>6;
  if ((threadIdx.x&63)==0) red[w]=v;
  __syncthreads();
  float a = fmaxf(fmaxf(red[0],red[1]),fmaxf(red[2],red[3]));
  float b = fmaxf(fmaxf(red[4],red[5]),fmaxf(red[6],red[7]));
  return fmaxf(a,b);
}

__device__ __forceinline__ float row_score(const float4* v, const float* wk,
                                           const float* g, const float* bt){
  float sum=0.f;
  #pragma unroll
  for (int i=0;i<16;++i) sum += v[i].x+v[i].y+v[i].z+v[i].w;
  float mu = sum*(1.f/64.f);
  float ssq=0.f;
  #pragma unroll
  for (int i=0;i<16;++i){ float dx=v[i].x-mu,dy=v[i].y-mu,dz=v[i].z-mu,dw=v[i].w-mu;
                          ssq+=dx*dx+dy*dy+dz*dz+dw*dw; }
  float rstd = rsqrtf(ssq*(1.f/64.f)+EPSF);
  float sc=0.f;
  #pragma unroll
  for (int i=0;i<16;++i){ int h=i*4;
    sc += ((v[i].x-mu)*rstd*g[h  ]+bt[h  ])*wk[h  ];
    sc += ((v[i].y-mu)*rstd*g[h+1]+bt[h+1])*wk[h+1];
    sc += ((v[i].z-mu)*rstd*g[h+2]+bt[h+2])*wk[h+2];
    sc += ((v[i].w-mu)*rstd*g[h+3]+bt[h+3])*wk[h+3];
  }
  return sc;
}

// LDS mem row <-> float4[16]
__device__ __forceinline__ void load_row_l(const unsigned* rp, float4* rr){
  const uint4* r16 = (const uint4*)rp;
  #pragma unroll
  for (int j=0;j<8;++j){
    uint4 q = r16[j];
    rr[2*j]   = make_float4(bl(q.x),bh(q.x),bl(q.y),bh(q.y));
    rr[2*j+1] = make_float4(bl(q.z),bh(q.z),bl(q.w),bh(q.w));
  }
}
__device__ __forceinline__ void store_row_l(unsigned* rp, const float4* rr){
  uint4* r16 = (uint4*)rp;
  #pragma unroll
  for (int j=0;j<8;++j){
    uint4 q;
    q.x = pk2(rr[2*j].x,   rr[2*j].y);
    q.y = pk2(rr[2*j].z,   rr[2*j].w);
    q.z = pk2(rr[2*j+1].x, rr[2*j+1].y);
    q.w = pk2(rr[2*j+1].z, rr[2*j+1].w);
    r16[j] = q;
  }
}

// logits tile (bf16 w_p, bf16 orow agent loads) — uses ws GEMM region
__device__ void logits_tile(const Params& p, int w, int tid, int tprev, float* ws){
  const unsigned* ob16 = p.orow16 + (size_t)(tprev&1)*BB*(PO/2);
  int cgl = w & 15, bg = w >> 4;
  int sub = tid >> 8, stid = tid & 255;
  int tb = stid >> 4, cq = stid & 15;
  int ar = tb, ac = cq << 2;
  int b0 = bg*16, col0 = cgl*64;
  float (*A_)[68]  = (float(*)[68])(ws + WS_GEMM_A);
  float (*Wt_)[68] = (float(*)[68])(ws + WS_GEMM_W);
  float (*Lc_)[68] = (float(*)[68])(ws + WS_GEMM_G);
  int c0 = cq*4;
  float acc0=0,acc1=0,acc2=0,acc3=0;
  uint2 aPre; uint4 wPre[2];
  const int NIT = 10;
  {
    int k0 = (0*2 + sub)*64;
    aPre = dloadu2(&ob16[((b0+ar)*PO + k0 + ac)>>1]);
    #pragma unroll
    for (int i2=0;i2<2;++i2){
      int li = i2*256 + stid; int ccl = li>>3; int kq = (stid&7)*8;
      wPre[i2] = *(const uint4*)&p.wp16[(size_t)(col0+ccl)*PO + k0 + kq];
    }
  }
  for (int it=0; it<NIT; ++it){
    A_[sub*16+ar][ac]=bl(aPre.x); A_[sub*16+ar][ac+1]=bh(aPre.x);
    A_[sub*16+ar][ac+2]=bl(aPre.y); A_[sub*16+ar][ac+3]=bh(aPre.y);
    #pragma unroll
    for (int i2=0;i2<2;++i2){
      int li = i2*256 + stid; int ccl = li>>3; int kq = (stid&7)*8;
      float f0=bl(wPre[i2].x),f1=bh(wPre[i2].x),f2=bl(wPre[i2].y),f3=bh(wPre[i2].y);
      float f4=bl(wPre[i2].z),f5=bh(wPre[i2].z),f6=bl(wPre[i2].w),f7=bh(wPre[i2].w);
      Wt_[sub*64+kq  ][ccl ^ ((((kq  )>>2)&7)<<2)] = f0;
      Wt_[sub*64+kq+1][ccl ^ ((((kq+1)>>2)&7)<<2)] = f1;
      Wt_[sub*64+kq+2][ccl ^ ((((kq+2)>>2)&7)<<2)] = f2;
      Wt_[sub*64+kq+3][ccl ^ ((((kq+3)>>2)&7)<<2)] = f3;
      Wt_[sub*64+kq+4][ccl ^ ((((kq+4)>>2)&7)<<2)] = f4;
      Wt_[sub*64+kq+5][ccl ^ ((((kq+5)>>2)&7)<<2)] = f5;
      Wt_[sub*64+kq+6][ccl ^ ((((kq+6)>>2)&7)<<2)] = f6;
      Wt_[sub*64+kq+7][ccl ^ ((((kq+7)>>2)&7)<<2)] = f7;
    }
    int nx = (it+1 < NIT) ? it+1 : it;
    {
      int k0 = (nx*2 + sub)*64;
      aPre = dloadu2(&ob16[((b0+ar)*PO + k0 + ac)>>1]);
      #pragma unroll
      for (int i2=0;i2<2;++i2){
        int li = i2*256 + stid; int ccl = li>>3; int kq = (stid&7)*8;
        wPre[i2] = *(const uint4*)&p.wp16[(size_t)(col0+ccl)*PO + k0 + kq];
      }
    }
    lds_barrier();
    #pragma unroll
    for (int kk=0;kk<16;++kk){
      float4 a4 = *(const float4*)&A_[sub*16+tb][kk*4];
      int cs = c0 ^ ((kk&7)<<2);
      float4 w0=*(const float4*)&Wt_[sub*64+kk*4  ][cs];
      float4 w1=*(const float4*)&Wt_[sub*64+kk*4+1][cs];
      float4 w2=*(const float4*)&Wt_[sub*64+kk*4+2][cs];
      float4 w3=*(const float4*)&Wt_[sub*64+kk*4+3][cs];
      acc0+=a4.x*w0.x; acc1+=a4.x*w0.y; acc2+=a4.x*w0.z; acc3+=a4.x*w0.w;
      acc0+=a4.y*w1.x; acc1+=a4.y*w1.y; acc2+=a4.y*w1.z; acc3+=a4.y*w1.w;
      acc0+=a4.z*w2.x; acc1+=a4.z*w2.y; acc2+=a4.z*w2.z; acc3+=a4.z*w2.w;
      acc0+=a4.w*w3.x; acc1+=a4.w*w3.y; acc2+=a4.w*w3.z; acc3+=a4.w*w3.w;
    }
    lds_barrier();
  }
  Lc_[sub*16+tb][c0]=acc0; Lc_[sub*16+tb][c0+1]=acc1;
  Lc_[sub*16+tb][c0+2]=acc2; Lc_[sub*16+tb][c0+3]=acc3;
  __syncthreads();
  if (tid < 256) {
    int tb2 = tid>>4, jl = tid&15;
    int cc0 = jl*4;
    int col = col0 + cc0;
    float4 o;
    o.x = Lc_[tb2][cc0]  +Lc_[16+tb2][cc0]   + p.b_p[col];
    o.y = Lc_[tb2][cc0+1]+Lc_[16+tb2][cc0+1] + p.b_p[col+1];
    o.z = Lc_[tb2][cc0+2]+Lc_[16+tb2][cc0+2] + p.b_p[col+2];
    o.w = Lc_[tb2][cc0+3]+Lc_[16+tb2][cc0+3] + p.b_p[col+3];
    *(float4*)&p.y[(size_t)((b0+tb2)*LL + tprev)*OO + col] = o;
  }
  __syncthreads();
}

__global__ __launch_bounds__(NT, 2) void dnc_all(Params p) {
  extern __shared__ unsigned dyn_lds[];
  unsigned* mrow = dyn_lds;                         // [512][MS] u32 (bf16 pairs)
  float* ws = (float*)(dyn_lds + 512*MS);           // WS_FLOATS floats
  __shared__ float red[8];
  const int blk = blockIdx.x, tid = threadIdx.x;
  const int NB = gridDim.x;
  const int bP = blk >> 2, chP = blk & 3;           // mem ownership: 4 chunks per b
  unsigned bnum = 0;

  // ---------------- P0: init + bf16 weight conversion ----------------
  {
    int gidx = blk*NT + tid, gstr = NB*NT;
    for (int i = gidx; i < (4096*CIN)/2; i += gstr){
      float2 f = *(const float2*)&p.w_ih[2*(size_t)i];
      dstoreu((unsigned*)p.wih16 + i, pk2(f.x, f.y));
    }
    for (int i = gidx; i < (4096*HH)/2; i += gstr){
      float2 f = *(const float2*)&p.w_hh[2*(size_t)i];
      dstoreu((unsigned*)p.whh16 + i, pk2(f.x, f.y));
    }
    for (int i = gidx; i < (OO*PO)/2; i += gstr){
      float2 f = *(const float2*)&p.w_p[2*(size_t)i];
      dstoreu((unsigned*)p.wp16 + i, pk2(f.x, f.y));
    }
    for (int i = gidx; i < 449*512; i += gstr){
      int gr = i >> 9, kp = (i & 511)*2;
      const float* wrow = (gr<256)? p.w_rk + (size_t)gr*HH :
                          (gr<320)? p.w_wk + (size_t)(gr-256)*HH :
                          (gr==320)? p.w_ws :
                          (gr<385)? p.w_er + (size_t)(gr-321)*HH :
                                    p.w_ad + (size_t)(gr-385)*HH;
      dstoreu((unsigned*)p.whd16 + i, pk2(wrow[kp], wrow[kp+1]));
    }
    for (int i = tid; i < 512*MS; i += NT) mrow[i] = 0u;     // LDS mem zero
    for (int i = gidx; i < (BB*HH)/2; i += gstr) dstoreu(&p.h16[i], 0u);
    if (blk < BB) {
      int b = blk;
      for (int i = tid; i < CIN; i += NT)
        ws[i] = (i < EE) ? p.x_emb[(size_t)(b*LL)*EE + i] : 0.f;
      __syncthreads();
      float s = 0.f;
      for (int i = tid; i < CIN; i += NT) s += ws[i];
      float mu = bsum(s, red) * (1.f/CIN);
      float ss = 0.f;
      for (int i = tid; i < CIN; i += NT) { float d = ws[i]-mu; ss += d*d; }
      float rstd = rsqrtf(bsum(ss, red)*(1.f/CIN) + EPSF);
      for (int i2 = tid; i2 < CIN/2; i2 += NT){
        float v0 = (ws[2*i2]-mu)*rstd*p.ln_in_g[2*i2] + p.ln_in_b[2*i2];
        float v1 = (ws[2*i2+1]-mu)*rstd*p.ln_in_g[2*i2+1] + p.ln_in_b[2*i2+1];
        dstoreu(&p.ci16[b*(CIN/2)+i2], pk2(v0, v1));
      }
    }
  }
  gbar(p.bar, ++bnum);

  for (int t = 0; t < LL; ++t) {
    const unsigned* hprev16 = p.h16 + (t & 1) * ((BB*HH)>>1);
    unsigned* hnew16 = p.h16 + ((t+1) & 1) * ((BB*HH)>>1);

    // -------- P1: gates GEMM + LSTM --------
    for (int w = blk; w < 256; w += NB) {
      int cgp = w & 63, bg = w >> 6;
      int sub = tid >> 8, stid = tid & 255;
      int tb = stid >> 4, cq = stid & 15;
      int ar = tb, ac = cq << 2;
      int b0 = bg*16, j0 = cgp*16;
      float (*A_)[68]  = (float(*)[68])(ws + WS_GEMM_A);
      float (*Wt_)[68] = (float(*)[68])(ws + WS_GEMM_W);
      float (*Gv_)[68] = (float(*)[68])(ws + WS_GEMM_G);
      int c0 = cq*4;
      float acc0=0,acc1=0,acc2=0,acc3=0;
      uint2 aPre; uint4 wPre[2];
      const int NIT = 14;
      {
        int k0 = sub*64;
        aPre = dloadu2(&p.ci16[((b0+ar)*CIN + k0 + ac)>>1]);
        #pragma unroll
        for (int i2=0;i2<2;++i2){
          int li = i2*256 + stid; int ccl = li>>3; int kq = (stid&7)*8;
          int gate = ccl>>4, jl = ccl&15;
          wPre[i2] = *(const uint4*)&p.wih16[(size_t)(gate*HH + j0 + jl)*CIN + k0 + kq];
        }
      }
      for (int it=0; it<NIT; ++it){
        A_[sub*16+ar][ac]=bl(aPre.x); A_[sub*16+ar][ac+1]=bh(aPre.x);
        A_[sub*16+ar][ac+2]=bl(aPre.y); A_[sub*16+ar][ac+3]=bh(aPre.y);
        #pragma unroll
        for (int i2=0;i2<2;++i2){
          int li = i2*256 + stid; int ccl = li>>3; int kq = (stid&7)*8;
          float f0=bl(wPre[i2].x),f1=bh(wPre[i2].x),f2=bl(wPre[i2].y),f3=bh(wPre[i2].y);
          float f4=bl(wPre[i2].z),f5=bh(wPre[i2].z),f6=bl(wPre[i2].w),f7=bh(wPre[i2].w);
          Wt_[sub*64+kq  ][ccl ^ ((((kq  )>>2)&7)<<2)] = f0;
          Wt_[sub*64+kq+1][ccl ^ ((((kq+1)>>2)&7)<<2)] = f1;
          Wt_[sub*64+kq+2][ccl ^ ((((kq+2)>>2)&7)<<2)] = f2;
          Wt_[sub*64+kq+3][ccl ^ ((((kq+3)>>2)&7)<<2)] = f3;
          Wt_[sub*64+kq+4][ccl ^ ((((kq+4)>>2)&7)<<2)] = f4;
          Wt_[sub*64+kq+5][ccl ^ ((((kq+5)>>2)&7)<<2)] = f5;
          Wt_[sub*64+kq+6][ccl ^ ((((kq+6)>>2)&7)<<2)] = f6;
          Wt_[sub*64+kq+7][ccl ^ ((((kq+7)>>2)&7)<<2)] = f7;
        }
        int nx = (it+1 < NIT) ? it+1 : it;
        {
          const unsigned* As16; const unsigned short* Ws16; int K, k0;
          if (nx < 6){ As16 = p.ci16;  Ws16 = p.wih16; K = CIN; k0 = (nx*2 + sub)*64; }
          else       { As16 = hprev16; Ws16 = p.whh16; K = HH;  k0 = ((nx-6)*2 + sub)*64; }
          aPre = dloadu2(&As16[((b0+ar)*K + k0 + ac)>>1]);
          #pragma unroll
          for (int i2=0;i2<2;++i2){
            int li = i2*256 + stid; int ccl = li>>3; int kq = (stid&7)*8;
            int gate = ccl>>4, jl = ccl&15;
            wPre[i2] = *(const uint4*)&Ws16[(size_t)(gate*HH + j0 + jl)*K + k0 + kq];
          }
        }
        lds_barrier();
        #pragma unroll
        for (int kk=0;kk<16;++kk){
          float4 a4 = *(const float4*)&A_[sub*16+tb][kk*4];
          int cs = c0 ^ ((kk&7)<<2);
          float4 w0=*(const float4*)&Wt_[sub*64+kk*4  ][cs];
          float4 w1=*(const float4*)&Wt_[sub*64+kk*4+1][cs];
          float4 w2=*(const float4*)&Wt_[sub*64+kk*4+2][cs];
          float4 w3=*(const float4*)&Wt_[sub*64+kk*4+3][cs];
          acc0+=a4.x*w0.x; acc1+=a4.x*w0.y; acc2+=a4.x*w0.z; acc3+=a4.x*w0.w;
          acc0+=a4.y*w1.x; acc1+=a4.y*w1.y; acc2+=a4.y*w1.z; acc3+=a4.y*w1.w;
          acc0+=a4.z*w2.x; acc1+=a4.z*w2.y; acc2+=a4.z*w2.z; acc3+=a4.z*w2.w;
          acc0+=a4.w*w3.x; acc1+=a4.w*w3.y; acc2+=a4.w*w3.z; acc3+=a4.w*w3.w;
        }
        lds_barrier();
      }
      Gv_[sub*16+tb][c0]=acc0; Gv_[sub*16+tb][c0+1]=acc1;
      Gv_[sub*16+tb][c0+2]=acc2; Gv_[sub*16+tb][c0+3]=acc3;
      __syncthreads();
      if (tid < 256) {
        int tb2 = tid>>4, jl = tid&15;
        int r0 = 0*HH + j0 + jl, r1 = 1*HH + j0 + jl, r2 = 2*HH + j0 + jl, r3 = 3*HH + j0 + jl;
        float gi = Gv_[tb2][jl]    + Gv_[16+tb2][jl]    + p.b_ih[r0]+p.b_hh[r0];
        float gf = Gv_[tb2][16+jl] + Gv_[16+tb2][16+jl] + p.b_ih[r1]+p.b_hh[r1];
        float gg = Gv_[tb2][32+jl] + Gv_[16+tb2][32+jl] + p.b_ih[r2]+p.b_hh[r2];
        float go = Gv_[tb2][48+jl] + Gv_[16+tb2][48+jl] + p.b_ih[r3]+p.b_hh[r3];
        int idx3 = (b0+tb2)*HH + j0 + jl;
        float cold = (t==0) ? 0.f : p.c[idx3];
        float cn = sigm(gf)*cold + sigm(gi)*tanhf(gg);
        float hv = sigm(go)*tanhf(cn);
        p.c[idx3] = cn;
        float hvn = __shfl_down(hv, 1, 64);
        if ((tid & 1) == 0)
          dstoreu(&hnew16[idx3>>1], pk2(hv, hvn));
        if (t == LL-1) { p.ht[idx3] = hv; p.ct[idx3] = cn; }
      }
      __syncthreads();
    }
    gbar(p.bar, ++bnum);

    // -------- P2: heads (redundant x4) + pass A write-scores --------
    {
      float* bcg = ws + WS_BCG;
      float* raw = ws + WS_RAW;
      float* pHn = ws + WS_PHN;
      if (tid < 64) { bcg[tid] = p.ln_m_g[tid]; bcg[64+tid] = p.ln_m_b[tid]; }
      unsigned hu = dloadu(&hnew16[(bP*HH>>1) + tid]);
      float hx = bl(hu), hy = bh(hu);
      float s = bsum(hx + hy, red);
      float mu = s * (1.f/HH);
      float d0 = hx-mu, d1 = hy-mu;
      float ssq = bsum(d0*d0 + d1*d1, red);
      float rstd = rsqrtf(ssq*(1.f/HH)+EPSF);
      pHn[tid*2]   = d0*rstd*p.ln_c_g[tid*2]   + p.ln_c_b[tid*2];
      pHn[tid*2+1] = d1*rstd*p.ln_c_g[tid*2+1] + p.ln_c_b[tid*2+1];
      __syncthreads();
      if (tid < 449) {
        int gr = tid;
        float bias;
        if (gr < 256)      bias = p.b_rk[gr];
        else if (gr < 320) bias = p.b_wk[gr-256];
        else if (gr == 320)bias = p.b_ws[0];
        else if (gr < 385) bias = p.b_er[gr-321];
        else               bias = p.b_ad[gr-385];
        const unsigned short* wr16 = p.whd16 + (size_t)gr*HH;
        float acc = bias;
        #pragma unroll 4
        for (int k=0;k<HH;k+=8){
          uint4 q = *(const uint4*)&wr16[k];
          acc += bl(q.x)*pHn[k  ] + bh(q.x)*pHn[k+1] + bl(q.y)*pHn[k+2] + bh(q.y)*pHn[k+3]
               + bl(q.z)*pHn[k+4] + bh(q.z)*pHn[k+5] + bl(q.w)*pHn[k+6] + bh(q.w)*pHn[k+7];
        }
        raw[tid] = acc;
      }
      __syncthreads();
      if (tid < 256) {
        int l = tid & 63;
        float v = raw[tid];
        float sv=v; for(int o=32;o>0;o>>=1) sv += __shfl_xor(sv,o,64);
        float m2 = sv*(1.f/64.f);
        float d = v-m2; float sq=d*d;
        for(int o=32;o>0;o>>=1) sq += __shfl_xor(sq,o,64);
        float rs = rsqrtf(sq*(1.f/64.f)+EPSF);
        ws[WS_RKN + tid] = d*rs*p.ln_rk_g[l] + p.ln_rk_b[l];
      } else if (tid < 320) {
        int l = tid - 256;
        float v = raw[256+l];
        float sv=v; for(int o=32;o>0;o>>=1) sv += __shfl_xor(sv,o,64);
        float m2 = sv*(1.f/64.f);
        float d=v-m2; float sq=d*d;
        for(int o=32;o>0;o>>=1) sq += __shfl_xor(sq,o,64);
        float rs = rsqrtf(sq*(1.f/64.f)+EPSF);
        ws[WS_WKN + l] = d*rs*p.ln_wk_g[l] + p.ln_wk_b[l];
      } else if (tid < 384) {
        int l = tid - 320; ws[WS_ERS + l] = sigm(raw[321+l]);
      } else if (tid < 448) {
        int l = tid - 384; ws[WS_ADS + l] = tanhf(raw[385+l]);
      } else if (tid == 448) {
        ws[WS_WSS] = sigm(raw[320]);
      }
      __syncthreads();
      float4 rr[16];
      load_row_l(mrow + tid*MS, rr);
      float sc = row_score(rr, ws+WS_WKN, bcg, bcg+64);
      ws[WS_SW + tid] = sc;
      float mx = bmax(sc, red);
      float se = bsum(expf(sc-mx), red);
      if (tid==0){ dstoref(&p.wpart[(bP*4+chP)*2], mx); dstoref(&p.wpart[(bP*4+chP)*2+1], se); }
    }
    gbar(p.bar, ++bnum);

    // -------- P3: mem update + read scores + chunk softmax + rv partials --------
    {
      float* bcg = ws + WS_BCG;
      float* srd = ws + WS_SRD;
      float* pRkn = ws + WS_RKN;
      float* pErs = ws + WS_ERS;
      float* pAds = ws + WS_ADS;
      float gmx = -3.4e38f, gsum = 0.f;
      #pragma unroll
      for (int cc=0; cc<4; ++cc) gmx = fmaxf(gmx, dloadf(&p.wpart[(bP*4+cc)*2]));
      #pragma unroll
      for (int cc=0; cc<4; ++cc)
        gsum += dloadf(&p.wpart[(bP*4+cc)*2+1]) * expf(dloadf(&p.wpart[(bP*4+cc)*2]) - gmx);
      float wstr = ws[WS_WSS];
      float ww = expf(ws[WS_SW + tid] - gmx)/gsum * wstr;
      unsigned* rp = mrow + tid*MS;
      float4 rr[16];
      load_row_l(rp, rr);
      #pragma unroll
      for (int i=0;i<16;++i){ int h=i*4;
        rr[i].x = rr[i].x*(1.f-ww*pErs[h  ]) + ww*pAds[h  ];
        rr[i].y = rr[i].y*(1.f-ww*pErs[h+1]) + ww*pAds[h+1];
        rr[i].z = rr[i].z*(1.f-ww*pErs[h+2]) + ww*pAds[h+2];
        rr[i].w = rr[i].w*(1.f-ww*pErs[h+3]) + ww*pAds[h+3];
      }
      store_row_l(rp, rr);
      float sum=0.f;
      #pragma unroll
      for (int i=0;i<16;++i) sum += rr[i].x+rr[i].y+rr[i].z+rr[i].w;
      float mu = sum*(1.f/64.f);
      float ssq=0.f;
      #pragma unroll
      for (int i=0;i<16;++i){ float dx=rr[i].x-mu,dy=rr[i].y-mu,dz=rr[i].z-mu,dw=rr[i].w-mu;
                              ssq+=dx*dx+dy*dy+dz*dz+dw*dw; }
      float rstd = rsqrtf(ssq*(1.f/64.f)+EPSF);
      float sN[4] = {0.f,0.f,0.f,0.f};
      #pragma unroll
      for (int i=0;i<16;++i){ int h=i*4;
        float n0=(rr[i].x-mu)*rstd*bcg[h  ]+bcg[64+h  ];
        float n1=(rr[i].y-mu)*rstd*bcg[h+1]+bcg[64+h+1];
        float n2=(rr[i].z-mu)*rstd*bcg[h+2]+bcg[64+h+2];
        float n3=(rr[i].w-mu)*rstd*bcg[h+3]+bcg[64+h+3];
        sN[0] += n0*pRkn[h    ]+n1*pRkn[h+1    ]+n2*pRkn[h+2    ]+n3*pRkn[h+3    ];
        sN[1] += n0*pRkn[64+h ]+n1*pRkn[64+h+1 ]+n2*pRkn[64+h+2 ]+n3*pRkn[64+h+3 ];
        sN[2] += n0*pRkn[128+h]+n1*pRkn[128+h+1]+n2*pRkn[128+h+2]+n3*pRkn[128+h+3];
        sN[3] += n0*pRkn[192+h]+n1*pRkn[192+h+1]+n2*pRkn[192+h+2]+n3*pRkn[192+h+3];
      }
      #pragma unroll
      for (int n=0;n<RR;++n){
        float mxn = bmax(sN[n], red);
        float sen = bsum(expf(sN[n]-mxn), red);
        srd[n*512 + tid] = expf(sN[n]-mxn);
        if (tid==0){
          dstoref(&p.rpart[(bP*4+chP)*8 + n*2], mxn);
          dstoref(&p.rpart[(bP*4+chP)*8 + n*2+1], sen);
        }
      }
      __syncthreads();
      int hs2 = (tid & 31) * 2, wg = tid >> 5;
      float a00=0,a01=0,a10=0,a11=0,a20=0,a21=0,a30=0,a31=0;
      for (int ml = wg; ml < 512; ml += 16){
        unsigned u = mrow[ml*MS + (hs2>>1)];
        float vlo = bl(u), vhi = bh(u);
        float w0 = srd[ml], w1 = srd[512+ml], w2 = srd[1024+ml], w3 = srd[1536+ml];
        a00 += w0*vlo; a01 += w0*vhi;
        a10 += w1*vlo; a11 += w1*vhi;
        a20 += w2*vlo; a21 += w2*vhi;
        a30 += w3*vlo; a31 += w3*vhi;
      }
      __syncthreads();
      float* part = ws + WS_PART;
      part[(0*16+wg)*64 + hs2] = a00; part[(0*16+wg)*64 + hs2+1] = a01;
      part[(1*16+wg)*64 + hs2] = a10; part[(1*16+wg)*64 + hs2+1] = a11;
      part[(2*16+wg)*64 + hs2] = a20; part[(2*16+wg)*64 + hs2+1] = a21;
      part[(3*16+wg)*64 + hs2] = a30; part[(3*16+wg)*64 + hs2+1] = a31;
      __syncthreads();
      if (tid < 256) {
        int n2 = tid>>6, h2 = tid&63;
        float v = 0.f;
        #pragma unroll
        for (int g2=0; g2<16; ++g2) v += part[(n2*16+g2)*64 + h2];
        dstoref(&p.rvpart[((bP*4+chP)*4 + n2)*64 + h2], v);
      }
    }
    gbar(p.bar, ++bnum);

    // -------- P4: rv combine + orow + ci (ch0) || logits(t-1) (ch1) --------
    if (chP == 0) {
      int b = bP;
      float* row   = ws + WS_ROW;
      float* cirow = ws + WS_CIROW;
      float* pHn   = ws + WS_PHN;
      if (tid < 256) {
        int n = tid>>6, h2 = tid&63;
        float gmxn = -3.4e38f;
        #pragma unroll
        for (int cc=0; cc<4; ++cc) gmxn = fmaxf(gmxn, dloadf(&p.rpart[(b*4+cc)*8 + n*2]));
        float den=0.f, num=0.f;
        #pragma unroll
        for (int cc=0; cc<4; ++cc){
          float e = expf(dloadf(&p.rpart[(b*4+cc)*8 + n*2]) - gmxn);
          den += dloadf(&p.rpart[(b*4+cc)*8 + n*2+1]) * e;
          num += dloadf(&p.rvpart[((b*4+cc)*4 + n)*64 + h2]) * e;
        }
        row[HH + tid] = num/den;
      }
      for (int i=tid;i<HH;i+=NT) row[i] = pHn[i];
      __syncthreads();
      float s=0.f; for (int i=tid;i<PO;i+=NT) s+=row[i];
      float mu = bsum(s,red)*(1.f/PO);
      float ss=0.f; for (int i=tid;i<PO;i+=NT){ float d=row[i]-mu; ss+=d*d; }
      float rstd = rsqrtf(bsum(ss,red)*(1.f/PO)+EPSF);
      unsigned* ob16 = p.orow16 + (size_t)(t&1)*BB*(PO/2);
      for (int i2=tid; i2<PO/2; i2+=NT){
        float v0 = (row[2*i2]-mu)*rstd*p.ln_o_g[2*i2]+p.ln_o_b[2*i2];
        float v1 = (row[2*i2+1]-mu)*rstd*p.ln_o_g[2*i2+1]+p.ln_o_b[2*i2+1];
        dstoreu(&ob16[b*(PO/2)+i2], pk2(v0, v1));
      }
      if (t+1 < LL) {
        for (int i=tid;i<CIN;i+=NT)
          cirow[i] = (i<EE)? p.x_emb[(size_t)(b*LL+t+1)*EE+i] : row[HH+(i-EE)];
        __syncthreads();
        float s2=0.f; for (int i=tid;i<CIN;i+=NT) s2+=cirow[i];
        float mu2 = bsum(s2,red)*(1.f/CIN);
        float ss2=0.f; for (int i=tid;i<CIN;i+=NT){ float d=cirow[i]-mu2; ss2+=d*d; }
        float rstd2 = rsqrtf(bsum(ss2,red)*(1.f/CIN)+EPSF);
        for (int i2=tid; i2<CIN/2; i2+=NT){
          float v0 = (cirow[2*i2]-mu2)*rstd2*p.ln_in_g[2*i2]+p.ln_in_b[2*i2];
          float v1 = (cirow[2*i2+1]-mu2)*rstd2*p.ln_in_g[2*i2+1]+p.ln_in_b[2*i2+1];
          dstoreu(&p.ci16[b*(CIN/2)+i2], pk2(v0, v1));
        }
      }
    } else if (chP == 1 && t > 0) {
      logits_tile(p, bP, tid, t-1, ws);
    }
    gbar(p.bar, ++bnum);
  }

  // ---------------- finale: LDS mem -> fp32 memT + logits(255) ----------------
  {
    float* dst = p.mem + ((size_t)bP*MM + chP*CSL)*HSZ;
    int ml = tid;
    const uint4* src = (const uint4*)(mrow + ml*MS);
    float4* d4 = (float4*)(dst + (size_t)ml*HSZ);
    #pragma unroll
    for (int j=0;j<8;++j){
      uint4 q = src[j];
      d4[2*j]   = make_float4(bl(q.x),bh(q.x),bl(q.y),bh(q.y));
      d4[2*j+1] = make_float4(bl(q.z),bh(q.z),bl(q.w),bh(q.w));
    }
  }
  if (chP == 1) logits_tile(p, bP, tid, LL-1, ws);
}

extern "C" void kernel_launch(void* const* d_in, const int* in_sizes, int n_in,
                              void* d_out, int out_size, void* d_ws, size_t ws_size,
                              hipStream_t stream) {
  Params prm;
  prm.x_emb  = (const float*)d_in[0];
  prm.ln_in_g= (const float*)d_in[1];
  prm.ln_in_b= (const float*)d_in[2];
  prm.w_ih   = (const float*)d_in[3];
  prm.w_hh   = (const float*)d_in[4];
  prm.b_ih   = (const float*)d_in[5];
  prm.b_hh   = (const float*)d_in[6];
  prm.ln_c_g = (const float*)d_in[7];
  prm.ln_c_b = (const float*)d_in[8];
  prm.w_rk   = (const float*)d_in[9];
  prm.b_rk   = (const float*)d_in[10];
  prm.w_wk   = (const float*)d_in[11];
  prm.b_wk   = (const float*)d_in[12];
  prm.w_ws   = (const float*)d_in[13];
  prm.b_ws   = (const float*)d_in[14];
  prm.w_er   = (const float*)d_in[15];
  prm.b_er   = (const float*)d_in[16];
  prm.w_ad   = (const float*)d_in[17];
  prm.b_ad   = (const float*)d_in[18];
  prm.ln_rk_g= (const float*)d_in[19];
  prm.ln_rk_b= (const float*)d_in[20];
  prm.ln_wk_g= (const float*)d_in[21];
  prm.ln_wk_b= (const float*)d_in[22];
  prm.ln_m_g = (const float*)d_in[23];
  prm.ln_m_b = (const float*)d_in[24];
  prm.ln_o_g = (const float*)d_in[25];
  prm.ln_o_b = (const float*)d_in[26];
  prm.w_p    = (const float*)d_in[27];
  prm.b_p    = (const float*)d_in[28];

  float* out = (float*)d_out;
  prm.y   = out + OUT_Y;
  prm.mem = out + OUT_MEM;
  prm.ht  = out + OUT_HT;
  prm.ct  = out + OUT_CT;

  // barrier region: 4 KB (root + 16 leaf lines + 16 release lines, 64B each)
  prm.bar = (unsigned*)d_ws;
  hipMemsetAsync(d_ws, 0, 4096, stream);

  float* ws = (float*)((char*)d_ws + 4096);
  size_t o = 0;
  prm.c      = ws + o; o += BB*HH;
  prm.h16    = (unsigned*)(ws + o); o += BB*HH;        // 2 x BB*HH/2 u32
  prm.ci16   = (unsigned*)(ws + o); o += (BB*CIN)/2;
  prm.orow16 = (unsigned*)(ws + o); o += BB*PO;        // 2 x BB*PO/2 u32
  prm.wpart  = ws + o; o += 256*2;
  prm.rpart  = ws + o; o += 256*8;
  prm.rvpart = ws + o; o += 256*4*64;
  prm.wih16  = (unsigned short*)(ws + o); o += (4096*CIN)/2;
  prm.whh16  = (unsigned short*)(ws + o); o += (4096*HH)/2;
  prm.wp16   = (unsigned short*)(ws + o); o += (OO*PO)/2;
  prm.whd16  = (unsigned short*)(ws + o); o += (449*HH)/2 + 64;

  hipFuncSetAttribute((const void*)dnc_all,
                      hipFuncAttributeMaxDynamicSharedMemorySize, DYN_BYTES);

  dnc_all<<<dim3(NB_REQ), dim3(NT), DYN_BYTES, stream>>>(prm);
}

// Round 15
// 31107.333 us; speedup vs baseline: 1.1265x; 1.1265x over previous
//
#include <hip/hip_runtime.h>
#include <math.h>

#define BB 64
#define LL 256
#define EE 512
#define HH 1024
#define MM 2048
#define HSZ 64
#define RR 4
#define CIN 768
#define PO 1280
#define OO 1024
#define EPSF 1e-5f
#define NT 512
#define NB_REQ 256
#define MS 36                 // LDS mem row stride in u32 (144 B, 16B-aligned, bank-spread)
#define CSL 512               // rows per chunk block

// ---- d_out layout (float offsets) ----
#define OUT_Y    0
#define OUT_MEM  (BB * LL * OO)
#define OUT_HT   (OUT_MEM + BB * MM * HSZ)
#define OUT_CT   (OUT_HT + BB * HH)

// ---- workspace (float offsets inside ws = dyn_lds after mem region) ----
#define WS_RAW   0
#define WS_SW    512
#define WS_SRD   1024          // 4*512
#define WS_BCG   3072          // 128
#define WS_PHN   3200          // 1024
#define WS_RKN   4224          // 256
#define WS_WKN   4480
#define WS_ERS   4544
#define WS_ADS   4608
#define WS_WSS   4672
#define WS_PART  5120          // 4096 (P3 staging)
#define WS_ROW   5120          // 1280 (P4, different phase)
#define WS_CIROW 6400          // 768
#define WS_GEMM_A  0
#define WS_GEMM_W  2176
#define WS_GEMM_G  10880
#define WS_FLOATS  13056
#define DYN_BYTES ((512*MS + WS_FLOATS) * 4)

struct Params {
  const float *x_emb, *ln_in_g, *ln_in_b, *w_ih, *w_hh, *b_ih, *b_hh;
  const float *ln_c_g, *ln_c_b, *w_rk, *b_rk, *w_wk, *b_wk, *w_ws, *b_ws;
  const float *w_er, *b_er, *w_ad, *b_ad, *ln_rk_g, *ln_rk_b, *ln_wk_g, *ln_wk_b;
  const float *ln_m_g, *ln_m_b, *ln_o_g, *ln_o_b, *w_p, *b_p;
  float *y, *mem, *ht, *ct;
  float *c, *wpart, *rpart, *rvpart;
  unsigned *h16, *ci16, *orow16;
  unsigned short *wih16, *whh16, *wp16, *whd16;
  unsigned *bar;
};

__device__ __forceinline__ float sigm(float x){ return 1.f/(1.f+expf(-x)); }
__device__ __forceinline__ float bl(unsigned u){ return __uint_as_float(u<<16); }
__device__ __forceinline__ float bh(unsigned u){ return __uint_as_float(u & 0xffff0000u); }
__device__ __forceinline__ unsigned pk2(float a, float b){
  unsigned ua = __float_as_uint(a), ub = __float_as_uint(b);
  ua = (ua + 0x7fffu + ((ua>>16)&1u)) >> 16;
  ub = (ub + 0x7fffu + ((ub>>16)&1u)) >> 16;
  return ua | (ub<<16);
}

// agent-scope coherent accessors for CROSS-BLOCK tensors
__device__ __forceinline__ unsigned dloadu(const unsigned* p){
  return __hip_atomic_load(p, __ATOMIC_RELAXED, __HIP_MEMORY_SCOPE_AGENT);
}
__device__ __forceinline__ uint2 dloadu2(const unsigned* p){
  unsigned long long u = __hip_atomic_load((const unsigned long long*)p,
                                           __ATOMIC_RELAXED, __HIP_MEMORY_SCOPE_AGENT);
  uint2 r; r.x = (unsigned)(u & 0xffffffffull); r.y = (unsigned)(u >> 32); return r;
}
__device__ __forceinline__ void dstoreu(unsigned* p, unsigned v){
  __hip_atomic_store(p, v, __ATOMIC_RELAXED, __HIP_MEMORY_SCOPE_AGENT);
}
__device__ __forceinline__ float dloadf(const float* p){
  return __hip_atomic_load(p, __ATOMIC_RELAXED, __HIP_MEMORY_SCOPE_AGENT);
}
__device__ __forceinline__ void dstoref(float* p, float v){
  __hip_atomic_store(p, v, __ATOMIC_RELAXED, __HIP_MEMORY_SCOPE_AGENT);
}

__device__ __forceinline__ void lds_barrier() {
  asm volatile("s_waitcnt lgkmcnt(0)" ::: "memory");
  __builtin_amdgcn_sched_barrier(0);
  __builtin_amdgcn_s_barrier();
  __builtin_amdgcn_sched_barrier(0);
}

// 2-level tree grid barrier: 16 leaves x 16 blocks, all counters on own 64B lines.
__device__ __forceinline__ void gbar(unsigned* bar, unsigned bnum) {
  __syncthreads();
  if (threadIdx.x == 0) {
    asm volatile("s_waitcnt vmcnt(0)" ::: "memory");
    int g = blockIdx.x & 15;
    unsigned a = __hip_atomic_fetch_add(&bar[16 + g*16], 1u,
                    __ATOMIC_RELAXED, __HIP_MEMORY_SCOPE_AGENT) + 1u;
    if (a == bnum * 16u) {
      unsigned r = __hip_atomic_fetch_add(&bar[0], 1u,
                      __ATOMIC_RELAXED, __HIP_MEMORY_SCOPE_AGENT) + 1u;
      if (r == bnum * 16u) {
        #pragma unroll
        for (int i=0;i<16;++i)
          __hip_atomic_fetch_add(&bar[512 + i*16], 1u,
                                 __ATOMIC_RELAXED, __HIP_MEMORY_SCOPE_AGENT);
      }
    }
    while (__hip_atomic_load(&bar[512 + g*16], __ATOMIC_RELAXED,
                             __HIP_MEMORY_SCOPE_AGENT) < bnum) {
      __builtin_amdgcn_s_sleep(8);
    }
    asm volatile("" ::: "memory");
  }
  __syncthreads();
}

__device__ __forceinline__ float bsum(float v, volatile float* red){
  __syncthreads();
  for (int o=32;o>0;o>>=1) v += __shfl_down(v,o,64);
  int w = threadIdx.x>>6;
  if ((threadIdx.x&63)==0) red[w]=v;
  __syncthreads();
  return red[0]+red[1]+red[2]+red[3]+red[4]+red[5]+red[6]+red[7];
}
__device__ __forceinline__ float bmax(float v, volatile float* red){
  __syncthreads();
  for (int o=32;o>0;o>>=1) v = fmaxf(v,__shfl_down(v,o,64));
  int w = threadIdx.x>>6;
  if ((threadIdx.x&63)==0) red[w]=v;
  __syncthreads();
  float a = fmaxf(fmaxf(red[0],red[1]),fmaxf(red[2],red[3]));
  float b = fmaxf(fmaxf(red[4],red[5]),fmaxf(red[6],red[7]));
  return fmaxf(a,b);
}

__device__ __forceinline__ float row_score(const float4* v, const float* wk,
                                           const float* g, const float* bt){
  float sum=0.f;
  #pragma unroll
  for (int i=0;i<16;++i) sum += v[i].x+v[i].y+v[i].z+v[i].w;
  float mu = sum*(1.f/64.f);
  float ssq=0.f;
  #pragma unroll
  for (int i=0;i<16;++i){ float dx=v[i].x-mu,dy=v[i].y-mu,dz=v[i].z-mu,dw=v[i].w-mu;
                          ssq+=dx*dx+dy*dy+dz*dz+dw*dw; }
  float rstd = rsqrtf(ssq*(1.f/64.f)+EPSF);
  float sc=0.f;
  #pragma unroll
  for (int i=0;i<16;++i){ int h=i*4;
    sc += ((v[i].x-mu)*rstd*g[h  ]+bt[h  ])*wk[h  ];
    sc += ((v[i].y-mu)*rstd*g[h+1]+bt[h+1])*wk[h+1];
    sc += ((v[i].z-mu)*rstd*g[h+2]+bt[h+2])*wk[h+2];
    sc += ((v[i].w-mu)*rstd*g[h+3]+bt[h+3])*wk[h+3];
  }
  return sc;
}

// LDS mem row <-> float4[16]
__device__ __forceinline__ void load_row_l(const unsigned* rp, float4* rr){
  const uint4* r16 = (const uint4*)rp;
  #pragma unroll
  for (int j=0;j<8;++j){
    uint4 q = r16[j];
    rr[2*j]   = make_float4(bl(q.x),bh(q.x),bl(q.y),bh(q.y));
    rr[2*j+1] = make_float4(bl(q.z),bh(q.z),bl(q.w),bh(q.w));
  }
}
__device__ __forceinline__ void store_row_l(unsigned* rp, const float4* rr){
  uint4* r16 = (uint4*)rp;
  #pragma unroll
  for (int j=0;j<8;++j){
    uint4 q;
    q.x = pk2(rr[2*j].x,   rr[2*j].y);
    q.y = pk2(rr[2*j].z,   rr[2*j].w);
    q.z = pk2(rr[2*j+1].x, rr[2*j+1].y);
    q.w = pk2(rr[2*j+1].z, rr[2*j+1].w);
    r16[j] = q;
  }
}

// logits tile (bf16 w_p, bf16 orow agent loads) — uses ws GEMM region
__device__ void logits_tile(const Params& p, int w, int tid, int tprev, float* ws){
  const unsigned* ob16 = p.orow16 + (size_t)(tprev&1)*BB*(PO/2);
  int cgl = w & 15, bg = w >> 4;
  int sub = tid >> 8, stid = tid & 255;
  int tb = stid >> 4, cq = stid & 15;
  int ar = tb, ac = cq << 2;
  int b0 = bg*16, col0 = cgl*64;
  float (*A_)[68]  = (float(*)[68])(ws + WS_GEMM_A);
  float (*Wt_)[68] = (float(*)[68])(ws + WS_GEMM_W);
  float (*Lc_)[68] = (float(*)[68])(ws + WS_GEMM_G);
  int c0 = cq*4;
  float acc0=0,acc1=0,acc2=0,acc3=0;
  uint2 aPre; uint4 wPre[2];
  const int NIT = 10;
  {
    int k0 = (0*2 + sub)*64;
    aPre = dloadu2(&ob16[((b0+ar)*PO + k0 + ac)>>1]);
    #pragma unroll
    for (int i2=0;i2<2;++i2){
      int li = i2*256 + stid; int ccl = li>>3; int kq = (stid&7)*8;
      wPre[i2] = *(const uint4*)&p.wp16[(size_t)(col0+ccl)*PO + k0 + kq];
    }
  }
  for (int it=0; it<NIT; ++it){
    A_[sub*16+ar][ac]=bl(aPre.x); A_[sub*16+ar][ac+1]=bh(aPre.x);
    A_[sub*16+ar][ac+2]=bl(aPre.y); A_[sub*16+ar][ac+3]=bh(aPre.y);
    #pragma unroll
    for (int i2=0;i2<2;++i2){
      int li = i2*256 + stid; int ccl = li>>3; int kq = (stid&7)*8;
      float f0=bl(wPre[i2].x),f1=bh(wPre[i2].x),f2=bl(wPre[i2].y),f3=bh(wPre[i2].y);
      float f4=bl(wPre[i2].z),f5=bh(wPre[i2].z),f6=bl(wPre[i2].w),f7=bh(wPre[i2].w);
      Wt_[sub*64+kq  ][ccl ^ ((((kq  )>>2)&7)<<2)] = f0;
      Wt_[sub*64+kq+1][ccl ^ ((((kq+1)>>2)&7)<<2)] = f1;
      Wt_[sub*64+kq+2][ccl ^ ((((kq+2)>>2)&7)<<2)] = f2;
      Wt_[sub*64+kq+3][ccl ^ ((((kq+3)>>2)&7)<<2)] = f3;
      Wt_[sub*64+kq+4][ccl ^ ((((kq+4)>>2)&7)<<2)] = f4;
      Wt_[sub*64+kq+5][ccl ^ ((((kq+5)>>2)&7)<<2)] = f5;
      Wt_[sub*64+kq+6][ccl ^ ((((kq+6)>>2)&7)<<2)] = f6;
      Wt_[sub*64+kq+7][ccl ^ ((((kq+7)>>2)&7)<<2)] = f7;
    }
    int nx = (it+1 < NIT) ? it+1 : it;
    {
      int k0 = (nx*2 + sub)*64;
      aPre = dloadu2(&ob16[((b0+ar)*PO + k0 + ac)>>1]);
      #pragma unroll
      for (int i2=0;i2<2;++i2){
        int li = i2*256 + stid; int ccl = li>>3; int kq = (stid&7)*8;
        wPre[i2] = *(const uint4*)&p.wp16[(size_t)(col0+ccl)*PO + k0 + kq];
      }
    }
    lds_barrier();
    #pragma unroll
    for (int kk=0;kk<16;++kk){
      float4 a4 = *(const float4*)&A_[sub*16+tb][kk*4];
      int cs = c0 ^ ((kk&7)<<2);
      float4 w0=*(const float4*)&Wt_[sub*64+kk*4  ][cs];
      float4 w1=*(const float4*)&Wt_[sub*64+kk*4+1][cs];
      float4 w2=*(const float4*)&Wt_[sub*64+kk*4+2][cs];
      float4 w3=*(const float4*)&Wt_[sub*64+kk*4+3][cs];
      acc0+=a4.x*w0.x; acc1+=a4.x*w0.y; acc2+=a4.x*w0.z; acc3+=a4.x*w0.w;
      acc0+=a4.y*w1.x; acc1+=a4.y*w1.y; acc2+=a4.y*w1.z; acc3+=a4.y*w1.w;
      acc0+=a4.z*w2.x; acc1+=a4.z*w2.y; acc2+=a4.z*w2.z; acc3+=a4.z*w2.w;
      acc0+=a4.w*w3.x; acc1+=a4.w*w3.y; acc2+=a4.w*w3.z; acc3+=a4.w*w3.w;
    }
    lds_barrier();
  }
  Lc_[sub*16+tb][c0]=acc0; Lc_[sub*16+tb][c0+1]=acc1;
  Lc_[sub*16+tb][c0+2]=acc2; Lc_[sub*16+tb][c0+3]=acc3;
  __syncthreads();
  if (tid < 256) {
    int tb2 = tid>>4, jl = tid&15;
    int cc0 = jl*4;
    int col = col0 + cc0;
    float4 o;
    o.x = Lc_[tb2][cc0]  +Lc_[16+tb2][cc0]   + p.b_p[col];
    o.y = Lc_[tb2][cc0+1]+Lc_[16+tb2][cc0+1] + p.b_p[col+1];
    o.z = Lc_[tb2][cc0+2]+Lc_[16+tb2][cc0+2] + p.b_p[col+2];
    o.w = Lc_[tb2][cc0+3]+Lc_[16+tb2][cc0+3] + p.b_p[col+3];
    *(float4*)&p.y[(size_t)((b0+tb2)*LL + tprev)*OO + col] = o;
  }
  __syncthreads();
}

__global__ __launch_bounds__(NT, 2) void dnc_all(Params p) {
  extern __shared__ unsigned dyn_lds[];
  unsigned* mrow = dyn_lds;                         // [512][MS] u32 (bf16 pairs)
  float* ws = (float*)(dyn_lds + 512*MS);           // WS_FLOATS floats
  __shared__ float red[8];
  const int blk = blockIdx.x, tid = threadIdx.x;
  const int NB = gridDim.x;
  const int bP = blk >> 2, chP = blk & 3;           // mem ownership: 4 chunks per b
  // XCD-aware logits tile for this block (used when chP==1): bijection of bP
  // grouping cgl%8 by bP parity so each logits-XCD's w_p half stays L2-resident.
  const int wlog = ((bP & 1) << 3) | ((bP >> 1) & 7) | (bP & 48);
  unsigned bnum = 0;

  // ---------------- P0: init + bf16 weight conversion ----------------
  {
    int gidx = blk*NT + tid, gstr = NB*NT;
    for (int i = gidx; i < (4096*CIN)/2; i += gstr){
      float2 f = *(const float2*)&p.w_ih[2*(size_t)i];
      dstoreu((unsigned*)p.wih16 + i, pk2(f.x, f.y));
    }
    for (int i = gidx; i < (4096*HH)/2; i += gstr){
      float2 f = *(const float2*)&p.w_hh[2*(size_t)i];
      dstoreu((unsigned*)p.whh16 + i, pk2(f.x, f.y));
    }
    for (int i = gidx; i < (OO*PO)/2; i += gstr){
      float2 f = *(const float2*)&p.w_p[2*(size_t)i];
      dstoreu((unsigned*)p.wp16 + i, pk2(f.x, f.y));
    }
    for (int i = gidx; i < 449*512; i += gstr){
      int gr = i >> 9, kp = (i & 511)*2;
      const float* wrow = (gr<256)? p.w_rk + (size_t)gr*HH :
                          (gr<320)? p.w_wk + (size_t)(gr-256)*HH :
                          (gr==320)? p.w_ws :
                          (gr<385)? p.w_er + (size_t)(gr-321)*HH :
                                    p.w_ad + (size_t)(gr-385)*HH;
      dstoreu((unsigned*)p.whd16 + i, pk2(wrow[kp], wrow[kp+1]));
    }
    for (int i = tid; i < 512*MS; i += NT) mrow[i] = 0u;     // LDS mem zero
    for (int i = gidx; i < (BB*HH)/2; i += gstr) dstoreu(&p.h16[i], 0u);
    if (blk < BB) {
      int b = blk;
      for (int i = tid; i < CIN; i += NT)
        ws[i] = (i < EE) ? p.x_emb[(size_t)(b*LL)*EE + i] : 0.f;
      __syncthreads();
      float s = 0.f;
      for (int i = tid; i < CIN; i += NT) s += ws[i];
      float mu = bsum(s, red) * (1.f/CIN);
      float ss = 0.f;
      for (int i = tid; i < CIN; i += NT) { float d = ws[i]-mu; ss += d*d; }
      float rstd = rsqrtf(bsum(ss, red)*(1.f/CIN) + EPSF);
      for (int i2 = tid; i2 < CIN/2; i2 += NT){
        float v0 = (ws[2*i2]-mu)*rstd*p.ln_in_g[2*i2] + p.ln_in_b[2*i2];
        float v1 = (ws[2*i2+1]-mu)*rstd*p.ln_in_g[2*i2+1] + p.ln_in_b[2*i2+1];
        dstoreu(&p.ci16[b*(CIN/2)+i2], pk2(v0, v1));
      }
    }
  }
  gbar(p.bar, ++bnum);

  for (int t = 0; t < LL; ++t) {
    const unsigned* hprev16 = p.h16 + (t & 1) * ((BB*HH)>>1);
    unsigned* hnew16 = p.h16 + ((t+1) & 1) * ((BB*HH)>>1);

    // -------- P1: gates GEMM + LSTM (XCD-aligned cgp: cgp%8 == blk%8) --------
    for (int w = blk; w < 256; w += NB) {
      int cgp = (w & 7) | (((w >> 3) & 7) << 3);   // XCD-swizzled column-group
      int bg = w >> 6;
      int sub = tid >> 8, stid = tid & 255;
      int tb = stid >> 4, cq = stid & 15;
      int ar = tb, ac = cq << 2;
      int b0 = bg*16, j0 = cgp*16;
      float (*A_)[68]  = (float(*)[68])(ws + WS_GEMM_A);
      float (*Wt_)[68] = (float(*)[68])(ws + WS_GEMM_W);
      float (*Gv_)[68] = (float(*)[68])(ws + WS_GEMM_G);
      int c0 = cq*4;
      float acc0=0,acc1=0,acc2=0,acc3=0;
      uint2 aPre; uint4 wPre[2];
      const int NIT = 14;
      {
        int k0 = sub*64;
        aPre = dloadu2(&p.ci16[((b0+ar)*CIN + k0 + ac)>>1]);
        #pragma unroll
        for (int i2=0;i2<2;++i2){
          int li = i2*256 + stid; int ccl = li>>3; int kq = (stid&7)*8;
          int gate = ccl>>4, jl = ccl&15;
          wPre[i2] = *(const uint4*)&p.wih16[(size_t)(gate*HH + j0 + jl)*CIN + k0 + kq];
        }
      }
      for (int it=0; it<NIT; ++it){
        A_[sub*16+ar][ac]=bl(aPre.x); A_[sub*16+ar][ac+1]=bh(aPre.x);
        A_[sub*16+ar][ac+2]=bl(aPre.y); A_[sub*16+ar][ac+3]=bh(aPre.y);
        #pragma unroll
        for (int i2=0;i2<2;++i2){
          int li = i2*256 + stid; int ccl = li>>3; int kq = (stid&7)*8;
          float f0=bl(wPre[i2].x),f1=bh(wPre[i2].x),f2=bl(wPre[i2].y),f3=bh(wPre[i2].y);
          float f4=bl(wPre[i2].z),f5=bh(wPre[i2].z),f6=bl(wPre[i2].w),f7=bh(wPre[i2].w);
          Wt_[sub*64+kq  ][ccl ^ ((((kq  )>>2)&7)<<2)] = f0;
          Wt_[sub*64+kq+1][ccl ^ ((((kq+1)>>2)&7)<<2)] = f1;
          Wt_[sub*64+kq+2][ccl ^ ((((kq+2)>>2)&7)<<2)] = f2;
          Wt_[sub*64+kq+3][ccl ^ ((((kq+3)>>2)&7)<<2)] = f3;
          Wt_[sub*64+kq+4][ccl ^ ((((kq+4)>>2)&7)<<2)] = f4;
          Wt_[sub*64+kq+5][ccl ^ ((((kq+5)>>2)&7)<<2)] = f5;
          Wt_[sub*64+kq+6][ccl ^ ((((kq+6)>>2)&7)<<2)] = f6;
          Wt_[sub*64+kq+7][ccl ^ ((((kq+7)>>2)&7)<<2)] = f7;
        }
        int nx = (it+1 < NIT) ? it+1 : it;
        {
          const unsigned* As16; const unsigned short* Ws16; int K, k0;
          if (nx < 6){ As16 = p.ci16;  Ws16 = p.wih16; K = CIN; k0 = (nx*2 + sub)*64; }
          else       { As16 = hprev16; Ws16 = p.whh16; K = HH;  k0 = ((nx-6)*2 + sub)*64; }
          aPre = dloadu2(&As16[((b0+ar)*K + k0 + ac)>>1]);
          #pragma unroll
          for (int i2=0;i2<2;++i2){
            int li = i2*256 + stid; int ccl = li>>3; int kq = (stid&7)*8;
            int gate = ccl>>4, jl = ccl&15;
            wPre[i2] = *(const uint4*)&Ws16[(size_t)(gate*HH + j0 + jl)*K + k0 + kq];
          }
        }
        lds_barrier();
        #pragma unroll
        for (int kk=0;kk<16;++kk){
          float4 a4 = *(const float4*)&A_[sub*16+tb][kk*4];
          int cs = c0 ^ ((kk&7)<<2);
          float4 w0=*(const float4*)&Wt_[sub*64+kk*4  ][cs];
          float4 w1=*(const float4*)&Wt_[sub*64+kk*4+1][cs];
          float4 w2=*(const float4*)&Wt_[sub*64+kk*4+2][cs];
          float4 w3=*(const float4*)&Wt_[sub*64+kk*4+3][cs];
          acc0+=a4.x*w0.x; acc1+=a4.x*w0.y; acc2+=a4.x*w0.z; acc3+=a4.x*w0.w;
          acc0+=a4.y*w1.x; acc1+=a4.y*w1.y; acc2+=a4.y*w1.z; acc3+=a4.y*w1.w;
          acc0+=a4.z*w2.x; acc1+=a4.z*w2.y; acc2+=a4.z*w2.z; acc3+=a4.z*w2.w;
          acc0+=a4.w*w3.x; acc1+=a4.w*w3.y; acc2+=a4.w*w3.z; acc3+=a4.w*w3.w;
        }
        lds_barrier();
      }
      Gv_[sub*16+tb][c0]=acc0; Gv_[sub*16+tb][c0+1]=acc1;
      Gv_[sub*16+tb][c0+2]=acc2; Gv_[sub*16+tb][c0+3]=acc3;
      __syncthreads();
      if (tid < 256) {
        int tb2 = tid>>4, jl = tid&15;
        int r0 = 0*HH + j0 + jl, r1 = 1*HH + j0 + jl, r2 = 2*HH + j0 + jl, r3 = 3*HH + j0 + jl;
        float gi = Gv_[tb2][jl]    + Gv_[16+tb2][jl]    + p.b_ih[r0]+p.b_hh[r0];
        float gf = Gv_[tb2][16+jl] + Gv_[16+tb2][16+jl] + p.b_ih[r1]+p.b_hh[r1];
        float gg = Gv_[tb2][32+jl] + Gv_[16+tb2][32+jl] + p.b_ih[r2]+p.b_hh[r2];
        float go = Gv_[tb2][48+jl] + Gv_[16+tb2][48+jl] + p.b_ih[r3]+p.b_hh[r3];
        int idx3 = (b0+tb2)*HH + j0 + jl;
        float cold = (t==0) ? 0.f : p.c[idx3];
        float cn = sigm(gf)*cold + sigm(gi)*tanhf(gg);
        float hv = sigm(go)*tanhf(cn);
        p.c[idx3] = cn;
        float hvn = __shfl_down(hv, 1, 64);
        if ((tid & 1) == 0)
          dstoreu(&hnew16[idx3>>1], pk2(hv, hvn));
        if (t == LL-1) { p.ht[idx3] = hv; p.ct[idx3] = cn; }
      }
      __syncthreads();
    }
    gbar(p.bar, ++bnum);

    // -------- P2: heads (redundant x4) + pass A write-scores --------
    {
      float* bcg = ws + WS_BCG;
      float* raw = ws + WS_RAW;
      float* pHn = ws + WS_PHN;
      if (tid < 64) { bcg[tid] = p.ln_m_g[tid]; bcg[64+tid] = p.ln_m_b[tid]; }
      unsigned hu = dloadu(&hnew16[(bP*HH>>1) + tid]);
      float hx = bl(hu), hy = bh(hu);
      float s = bsum(hx + hy, red);
      float mu = s * (1.f/HH);
      float d0 = hx-mu, d1 = hy-mu;
      float ssq = bsum(d0*d0 + d1*d1, red);
      float rstd = rsqrtf(ssq*(1.f/HH)+EPSF);
      pHn[tid*2]   = d0*rstd*p.ln_c_g[tid*2]   + p.ln_c_b[tid*2];
      pHn[tid*2+1] = d1*rstd*p.ln_c_g[tid*2+1] + p.ln_c_b[tid*2+1];
      __syncthreads();
      if (tid < 449) {
        int gr = tid;
        float bias;
        if (gr < 256)      bias = p.b_rk[gr];
        else if (gr < 320) bias = p.b_wk[gr-256];
        else if (gr == 320)bias = p.b_ws[0];
        else if (gr < 385) bias = p.b_er[gr-321];
        else               bias = p.b_ad[gr-385];
        const unsigned short* wr16 = p.whd16 + (size_t)gr*HH;
        float acc = bias;
        #pragma unroll 4
        for (int k=0;k<HH;k+=8){
          uint4 q = *(const uint4*)&wr16[k];
          acc += bl(q.x)*pHn[k  ] + bh(q.x)*pHn[k+1] + bl(q.y)*pHn[k+2] + bh(q.y)*pHn[k+3]
               + bl(q.z)*pHn[k+4] + bh(q.z)*pHn[k+5] + bl(q.w)*pHn[k+6] + bh(q.w)*pHn[k+7];
        }
        raw[tid] = acc;
      }
      __syncthreads();
      if (tid < 256) {
        int l = tid & 63;
        float v = raw[tid];
        float sv=v; for(int o=32;o>0;o>>=1) sv += __shfl_xor(sv,o,64);
        float m2 = sv*(1.f/64.f);
        float d = v-m2; float sq=d*d;
        for(int o=32;o>0;o>>=1) sq += __shfl_xor(sq,o,64);
        float rs = rsqrtf(sq*(1.f/64.f)+EPSF);
        ws[WS_RKN + tid] = d*rs*p.ln_rk_g[l] + p.ln_rk_b[l];
      } else if (tid < 320) {
        int l = tid - 256;
        float v = raw[256+l];
        float sv=v; for(int o=32;o>0;o>>=1) sv += __shfl_xor(sv,o,64);
        float m2 = sv*(1.f/64.f);
        float d=v-m2; float sq=d*d;
        for(int o=32;o>0;o>>=1) sq += __shfl_xor(sq,o,64);
        float rs = rsqrtf(sq*(1.f/64.f)+EPSF);
        ws[WS_WKN + l] = d*rs*p.ln_wk_g[l] + p.ln_wk_b[l];
      } else if (tid < 384) {
        int l = tid - 320; ws[WS_ERS + l] = sigm(raw[321+l]);
      } else if (tid < 448) {
        int l = tid - 384; ws[WS_ADS + l] = tanhf(raw[385+l]);
      } else if (tid == 448) {
        ws[WS_WSS] = sigm(raw[320]);
      }
      __syncthreads();
      float4 rr[16];
      load_row_l(mrow + tid*MS, rr);
      float sc = row_score(rr, ws+WS_WKN, bcg, bcg+64);
      ws[WS_SW + tid] = sc;
      float mx = bmax(sc, red);
      float se = bsum(expf(sc-mx), red);
      if (tid==0){ dstoref(&p.wpart[(bP*4+chP)*2], mx); dstoref(&p.wpart[(bP*4+chP)*2+1], se); }
    }
    gbar(p.bar, ++bnum);

    // -------- P3: mem update + read scores + chunk softmax + rv partials --------
    {
      float* bcg = ws + WS_BCG;
      float* srd = ws + WS_SRD;
      float* pRkn = ws + WS_RKN;
      float* pErs = ws + WS_ERS;
      float* pAds = ws + WS_ADS;
      float gmx = -3.4e38f, gsum = 0.f;
      #pragma unroll
      for (int cc=0; cc<4; ++cc) gmx = fmaxf(gmx, dloadf(&p.wpart[(bP*4+cc)*2]));
      #pragma unroll
      for (int cc=0; cc<4; ++cc)
        gsum += dloadf(&p.wpart[(bP*4+cc)*2+1]) * expf(dloadf(&p.wpart[(bP*4+cc)*2]) - gmx);
      float wstr = ws[WS_WSS];
      float ww = expf(ws[WS_SW + tid] - gmx)/gsum * wstr;
      unsigned* rp = mrow + tid*MS;
      float4 rr[16];
      load_row_l(rp, rr);
      #pragma unroll
      for (int i=0;i<16;++i){ int h=i*4;
        rr[i].x = rr[i].x*(1.f-ww*pErs[h  ]) + ww*pAds[h  ];
        rr[i].y = rr[i].y*(1.f-ww*pErs[h+1]) + ww*pAds[h+1];
        rr[i].z = rr[i].z*(1.f-ww*pErs[h+2]) + ww*pAds[h+2];
        rr[i].w = rr[i].w*(1.f-ww*pErs[h+3]) + ww*pAds[h+3];
      }
      store_row_l(rp, rr);
      float sum=0.f;
      #pragma unroll
      for (int i=0;i<16;++i) sum += rr[i].x+rr[i].y+rr[i].z+rr[i].w;
      float mu = sum*(1.f/64.f);
      float ssq=0.f;
      #pragma unroll
      for (int i=0;i<16;++i){ float dx=rr[i].x-mu,dy=rr[i].y-mu,dz=rr[i].z-mu,dw=rr[i].w-mu;
                              ssq+=dx*dx+dy*dy+dz*dz+dw*dw; }
      float rstd = rsqrtf(ssq*(1.f/64.f)+EPSF);
      float sN[4] = {0.f,0.f,0.f,0.f};
      #pragma unroll
      for (int i=0;i<16;++i){ int h=i*4;
        float n0=(rr[i].x-mu)*rstd*bcg[h  ]+bcg[64+h  ];
        float n1=(rr[i].y-mu)*rstd*bcg[h+1]+bcg[64+h+1];
        float n2=(rr[i].z-mu)*rstd*bcg[h+2]+bcg[64+h+2];
        float n3=(rr[i].w-mu)*rstd*bcg[h+3]+bcg[64+h+3];
        sN[0] += n0*pRkn[h    ]+n1*pRkn[h+1    ]+n2*pRkn[h+2    ]+n3*pRkn[h+3    ];
        sN[1] += n0*pRkn[64+h ]+n1*pRkn[64+h+1 ]+n2*pRkn[64+h+2 ]+n3*pRkn[64+h+3 ];
        sN[2] += n0*pRkn[128+h]+n1*pRkn[128+h+1]+n2*pRkn[128+h+2]+n3*pRkn[128+h+3];
        sN[3] += n0*pRkn[192+h]+n1*pRkn[192+h+1]+n2*pRkn[192+h+2]+n3*pRkn[192+h+3];
      }
      #pragma unroll
      for (int n=0;n<RR;++n){
        float mxn = bmax(sN[n], red);
        float sen = bsum(expf(sN[n]-mxn), red);
        srd[n*512 + tid] = expf(sN[n]-mxn);
        if (tid==0){
          dstoref(&p.rpart[(bP*4+chP)*8 + n*2], mxn);
          dstoref(&p.rpart[(bP*4+chP)*8 + n*2+1], sen);
        }
      }
      __syncthreads();
      int hs2 = (tid & 31) * 2, wg = tid >> 5;
      float a00=0,a01=0,a10=0,a11=0,a20=0,a21=0,a30=0,a31=0;
      for (int ml = wg; ml < 512; ml += 16){
        unsigned u = mrow[ml*MS + (hs2>>1)];
        float vlo = bl(u), vhi = bh(u);
        float w0 = srd[ml], w1 = srd[512+ml], w2 = srd[1024+ml], w3 = srd[1536+ml];
        a00 += w0*vlo; a01 += w0*vhi;
        a10 += w1*vlo; a11 += w1*vhi;
        a20 += w2*vlo; a21 += w2*vhi;
        a30 += w3*vlo; a31 += w3*vhi;
      }
      __syncthreads();
      float* part = ws + WS_PART;
      part[(0*16+wg)*64 + hs2] = a00; part[(0*16+wg)*64 + hs2+1] = a01;
      part[(1*16+wg)*64 + hs2] = a10; part[(1*16+wg)*64 + hs2+1] = a11;
      part[(2*16+wg)*64 + hs2] = a20; part[(2*16+wg)*64 + hs2+1] = a21;
      part[(3*16+wg)*64 + hs2] = a30; part[(3*16+wg)*64 + hs2+1] = a31;
      __syncthreads();
      if (tid < 256) {
        int n2 = tid>>6, h2 = tid&63;
        float v = 0.f;
        #pragma unroll
        for (int g2=0; g2<16; ++g2) v += part[(n2*16+g2)*64 + h2];
        dstoref(&p.rvpart[((bP*4+chP)*4 + n2)*64 + h2], v);
      }
    }
    gbar(p.bar, ++bnum);

    // -------- P4: rv combine + orow + ci (ch0) || logits(t-1) (ch1, XCD-swizzled) --------
    if (chP == 0) {
      int b = bP;
      float* row   = ws + WS_ROW;
      float* cirow = ws + WS_CIROW;
      float* pHn   = ws + WS_PHN;
      if (tid < 256) {
        int n = tid>>6, h2 = tid&63;
        float gmxn = -3.4e38f;
        #pragma unroll
        for (int cc=0; cc<4; ++cc) gmxn = fmaxf(gmxn, dloadf(&p.rpart[(b*4+cc)*8 + n*2]));
        float den=0.f, num=0.f;
        #pragma unroll
        for (int cc=0; cc<4; ++cc){
          float e = expf(dloadf(&p.rpart[(b*4+cc)*8 + n*2]) - gmxn);
          den += dloadf(&p.rpart[(b*4+cc)*8 + n*2+1]) * e;
          num += dloadf(&p.rvpart[((b*4+cc)*4 + n)*64 + h2]) * e;
        }
        row[HH + tid] = num/den;
      }
      for (int i=tid;i<HH;i+=NT) row[i] = pHn[i];
      __syncthreads();
      float s=0.f; for (int i=tid;i<PO;i+=NT) s+=row[i];
      float mu = bsum(s,red)*(1.f/PO);
      float ss=0.f; for (int i=tid;i<PO;i+=NT){ float d=row[i]-mu; ss+=d*d; }
      float rstd = rsqrtf(bsum(ss,red)*(1.f/PO)+EPSF);
      unsigned* ob16 = p.orow16 + (size_t)(t&1)*BB*(PO/2);
      for (int i2=tid; i2<PO/2; i2+=NT){
        float v0 = (row[2*i2]-mu)*rstd*p.ln_o_g[2*i2]+p.ln_o_b[2*i2];
        float v1 = (row[2*i2+1]-mu)*rstd*p.ln_o_g[2*i2+1]+p.ln_o_b[2*i2+1];
        dstoreu(&ob16[b*(PO/2)+i2], pk2(v0, v1));
      }
      if (t+1 < LL) {
        for (int i=tid;i<CIN;i+=NT)
          cirow[i] = (i<EE)? p.x_emb[(size_t)(b*LL+t+1)*EE+i] : row[HH+(i-EE)];
        __syncthreads();
        float s2=0.f; for (int i=tid;i<CIN;i+=NT) s2+=cirow[i];
        float mu2 = bsum(s2,red)*(1.f/CIN);
        float ss2=0.f; for (int i=tid;i<CIN;i+=NT){ float d=cirow[i]-mu2; ss2+=d*d; }
        float rstd2 = rsqrtf(bsum(ss2,red)*(1.f/CIN)+EPSF);
        for (int i2=tid; i2<CIN/2; i2+=NT){
          float v0 = (cirow[2*i2]-mu2)*rstd2*p.ln_in_g[2*i2]+p.ln_in_b[2*i2];
          float v1 = (cirow[2*i2+1]-mu2)*rstd2*p.ln_in_g[2*i2+1]+p.ln_in_b[2*i2+1];
          dstoreu(&p.ci16[b*(CIN/2)+i2], pk2(v0, v1));
        }
      }
    } else if (chP == 1 && t > 0) {
      logits_tile(p, wlog, tid, t-1, ws);
    }
    gbar(p.bar, ++bnum);
  }

  // ---------------- finale: LDS mem -> fp32 memT + logits(255) ----------------
  {
    float* dst = p.mem + ((size_t)bP*MM + chP*CSL)*HSZ;
    int ml = tid;
    const uint4* src = (const uint4*)(mrow + ml*MS);
    float4* d4 = (float4*)(dst + (size_t)ml*HSZ);
    #pragma unroll
    for (int j=0;j<8;++j){
      uint4 q = src[j];
      d4[2*j]   = make_float4(bl(q.x),bh(q.x),bl(q.y),bh(q.y));
      d4[2*j+1] = make_float4(bl(q.z),bh(q.z),bl(q.w),bh(q.w));
    }
  }
  if (chP == 1) logits_tile(p, wlog, tid, LL-1, ws);
}

extern "C" void kernel_launch(void* const* d_in, const int* in_sizes, int n_in,
                              void* d_out, int out_size, void* d_ws, size_t ws_size,
                              hipStream_t stream) {
  Params prm;
  prm.x_emb  = (const float*)d_in[0];
  prm.ln_in_g= (const float*)d_in[1];
  prm.ln_in_b= (const float*)d_in[2];
  prm.w_ih   = (const float*)d_in[3];
  prm.w_hh   = (const float*)d_in[4];
  prm.b_ih   = (const float*)d_in[5];
  prm.b_hh   = (const float*)d_in[6];
  prm.ln_c_g = (const float*)d_in[7];
  prm.ln_c_b = (const float*)d_in[8];
  prm.w_rk   = (const float*)d_in[9];
  prm.b_rk   = (const float*)d_in[10];
  prm.w_wk   = (const float*)d_in[11];
  prm.b_wk   = (const float*)d_in[12];
  prm.w_ws   = (const float*)d_in[13];
  prm.b_ws   = (const float*)d_in[14];
  prm.w_er   = (const float*)d_in[15];
  prm.b_er   = (const float*)d_in[16];
  prm.w_ad   = (const float*)d_in[17];
  prm.b_ad   = (const float*)d_in[18];
  prm.ln_rk_g= (const float*)d_in[19];
  prm.ln_rk_b= (const float*)d_in[20];
  prm.ln_wk_g= (const float*)d_in[21];
  prm.ln_wk_b= (const float*)d_in[22];
  prm.ln_m_g = (const float*)d_in[23];
  prm.ln_m_b = (const float*)d_in[24];
  prm.ln_o_g = (const float*)d_in[25];
  prm.ln_o_b = (const float*)d_in[26];
  prm.w_p    = (const float*)d_in[27];
  prm.b_p    = (const float*)d_in[28];

  float* out = (float*)d_out;
  prm.y   = out + OUT_Y;
  prm.mem = out + OUT_MEM;
  prm.ht  = out + OUT_HT;
  prm.ct  = out + OUT_CT;

  // barrier region: 4 KB (root + 16 leaf lines + 16 release lines, 64B each)
  prm.bar = (unsigned*)d_ws;
  hipMemsetAsync(d_ws, 0, 4096, stream);

  float* ws = (float*)((char*)d_ws + 4096);
  size_t o = 0;
  prm.c      = ws + o; o += BB*HH;
  prm.h16    = (unsigned*)(ws + o); o += BB*HH;        // 2 x BB*HH/2 u32
  prm.ci16   = (unsigned*)(ws + o); o += (BB*CIN)/2;
  prm.orow16 = (unsigned*)(ws + o); o += BB*PO;        // 2 x BB*PO/2 u32
  prm.wpart  = ws + o; o += 256*2;
  prm.rpart  = ws + o; o += 256*8;
  prm.rvpart = ws + o; o += 256*4*64;
  prm.wih16  = (unsigned short*)(ws + o); o += (4096*CIN)/2;
  prm.whh16  = (unsigned short*)(ws + o); o += (4096*HH)/2;
  prm.wp16   = (unsigned short*)(ws + o); o += (OO*PO)/2;
  prm.whd16  = (unsigned short*)(ws + o); o += (449*HH)/2 + 64;

  hipFuncSetAttribute((const void*)dnc_all,
                      hipFuncAttributeMaxDynamicSharedMemorySize, DYN_BYTES);

  dnc_all<<<dim3(NB_REQ), dim3(NT), DYN_BYTES, stream>>>(prm);
}

// Round 16
// 27215.475 us; speedup vs baseline: 1.2876x; 1.1430x over previous
//
#include <hip/hip_runtime.h>
#include <math.h>

#define BB 64
#define LL 256
#define EE 512
#define HH 1024
#define MM 2048
#define HSZ 64
#define RR 4
#define CIN 768
#define PO 1280
#define OO 1024
#define EPSF 1e-5f
#define NT 512
#define NB_REQ 256
#define MS 36
#define CSL 512

// ---- d_out layout (float offsets) ----
#define OUT_Y    0
#define OUT_MEM  (BB * LL * OO)
#define OUT_HT   (OUT_MEM + BB * MM * HSZ)
#define OUT_CT   (OUT_HT + BB * HH)

// ---- workspace (float offsets inside ws = dyn_lds after mem region) ----
#define WS_RAW   0
#define WS_SW    512
#define WS_SRD   1024
#define WS_BCG   3072
#define WS_PHN   3200
#define WS_RKN   4224
#define WS_WKN   4480
#define WS_ERS   4544
#define WS_ADS   4608
#define WS_WSS   4672
#define WS_PART  5120
#define WS_ROW   5120
#define WS_CIROW 6400
#define WS_GEMM_A  0
#define WS_GEMM_W  2176
#define WS_GEMM_G  10880
#define WS_FLOATS  13056
#define DYN_BYTES ((512*MS + WS_FLOATS) * 4)

struct Params {
  const float *x_emb, *ln_in_g, *ln_in_b, *w_ih, *w_hh, *b_ih, *b_hh;
  const float *ln_c_g, *ln_c_b, *w_rk, *b_rk, *w_wk, *b_wk, *w_ws, *b_ws;
  const float *w_er, *b_er, *w_ad, *b_ad, *ln_rk_g, *ln_rk_b, *ln_wk_g, *ln_wk_b;
  const float *ln_m_g, *ln_m_b, *ln_o_g, *ln_o_b, *w_p, *b_p;
  float *y, *mem, *ht, *ct;
  float *c, *wpart, *rpart, *rvpart, *rawbuf;
  unsigned *h16, *ci16, *orow16;
  unsigned short *wih16, *whh16, *wp16, *whd16;
  unsigned *bar;
};

__device__ __forceinline__ float sigm(float x){ return 1.f/(1.f+expf(-x)); }
__device__ __forceinline__ float bl(unsigned u){ return __uint_as_float(u<<16); }
__device__ __forceinline__ float bh(unsigned u){ return __uint_as_float(u & 0xffff0000u); }
__device__ __forceinline__ unsigned pk2(float a, float b){
  unsigned ua = __float_as_uint(a), ub = __float_as_uint(b);
  ua = (ua + 0x7fffu + ((ua>>16)&1u)) >> 16;
  ub = (ub + 0x7fffu + ((ub>>16)&1u)) >> 16;
  return ua | (ub<<16);
}

__device__ __forceinline__ unsigned dloadu(const unsigned* p){
  return __hip_atomic_load(p, __ATOMIC_RELAXED, __HIP_MEMORY_SCOPE_AGENT);
}
__device__ __forceinline__ uint2 dloadu2(const unsigned* p){
  unsigned long long u = __hip_atomic_load((const unsigned long long*)p,
                                           __ATOMIC_RELAXED, __HIP_MEMORY_SCOPE_AGENT);
  uint2 r; r.x = (unsigned)(u & 0xffffffffull); r.y = (unsigned)(u >> 32); return r;
}
__device__ __forceinline__ void dstoreu(unsigned* p, unsigned v){
  __hip_atomic_store(p, v, __ATOMIC_RELAXED, __HIP_MEMORY_SCOPE_AGENT);
}
__device__ __forceinline__ float dloadf(const float* p){
  return __hip_atomic_load(p, __ATOMIC_RELAXED, __HIP_MEMORY_SCOPE_AGENT);
}
__device__ __forceinline__ void dstoref(float* p, float v){
  __hip_atomic_store(p, v, __ATOMIC_RELAXED, __HIP_MEMORY_SCOPE_AGENT);
}

__device__ __forceinline__ void lds_barrier() {
  asm volatile("s_waitcnt lgkmcnt(0)" ::: "memory");
  __builtin_amdgcn_sched_barrier(0);
  __builtin_amdgcn_s_barrier();
  __builtin_amdgcn_sched_barrier(0);
}

// 2-level tree grid barrier: 16 leaves x 16 blocks, all counters on own 64B lines.
__device__ __forceinline__ void gbar(unsigned* bar, unsigned bnum) {
  __syncthreads();
  if (threadIdx.x == 0) {
    asm volatile("s_waitcnt vmcnt(0)" ::: "memory");
    int g = blockIdx.x & 15;
    unsigned a = __hip_atomic_fetch_add(&bar[16 + g*16], 1u,
                    __ATOMIC_RELAXED, __HIP_MEMORY_SCOPE_AGENT) + 1u;
    if (a == bnum * 16u) {
      unsigned r = __hip_atomic_fetch_add(&bar[0], 1u,
                      __ATOMIC_RELAXED, __HIP_MEMORY_SCOPE_AGENT) + 1u;
      if (r == bnum * 16u) {
        #pragma unroll
        for (int i=0;i<16;++i)
          __hip_atomic_fetch_add(&bar[512 + i*16], 1u,
                                 __ATOMIC_RELAXED, __HIP_MEMORY_SCOPE_AGENT);
      }
    }
    while (__hip_atomic_load(&bar[512 + g*16], __ATOMIC_RELAXED,
                             __HIP_MEMORY_SCOPE_AGENT) < bnum) {
      __builtin_amdgcn_s_sleep(8);
    }
    asm volatile("" ::: "memory");
  }
  __syncthreads();
}

__device__ __forceinline__ float bsum(float v, volatile float* red){
  __syncthreads();
  for (int o=32;o>0;o>>=1) v += __shfl_down(v,o,64);
  int w = threadIdx.x>>6;
  if ((threadIdx.x&63)==0) red[w]=v;
  __syncthreads();
  return red[0]+red[1]+red[2]+red[3]+red[4]+red[5]+red[6]+red[7];
}
__device__ __forceinline__ float bmax(float v, volatile float* red){
  __syncthreads();
  for (int o=32;o>0;o>>=1) v = fmaxf(v,__shfl_down(v,o,64));
  int w = threadIdx.x>>6;
  if ((threadIdx.x&63)==0) red[w]=v;
  __syncthreads();
  float a = fmaxf(fmaxf(red[0],red[1]),fmaxf(red[2],red[3]));
  float b = fmaxf(fmaxf(red[4],red[5]),fmaxf(red[6],red[7]));
  return fmaxf(a,b);
}

__device__ __forceinline__ float row_score(const float4* v, const float* wk,
                                           const float* g, const float* bt){
  float sum=0.f;
  #pragma unroll
  for (int i=0;i<16;++i) sum += v[i].x+v[i].y+v[i].z+v[i].w;
  float mu = sum*(1.f/64.f);
  float ssq=0.f;
  #pragma unroll
  for (int i=0;i<16;++i){ float dx=v[i].x-mu,dy=v[i].y-mu,dz=v[i].z-mu,dw=v[i].w-mu;
                          ssq+=dx*dx+dy*dy+dz*dz+dw*dw; }
  float rstd = rsqrtf(ssq*(1.f/64.f)+EPSF);
  float sc=0.f;
  #pragma unroll
  for (int i=0;i<16;++i){ int h=i*4;
    sc += ((v[i].x-mu)*rstd*g[h  ]+bt[h  ])*wk[h  ];
    sc += ((v[i].y-mu)*rstd*g[h+1]+bt[h+1])*wk[h+1];
    sc += ((v[i].z-mu)*rstd*g[h+2]+bt[h+2])*wk[h+2];
    sc += ((v[i].w-mu)*rstd*g[h+3]+bt[h+3])*wk[h+3];
  }
  return sc;
}

__device__ __forceinline__ void load_row_l(const unsigned* rp, float4* rr){
  const uint4* r16 = (const uint4*)rp;
  #pragma unroll
  for (int j=0;j<8;++j){
    uint4 q = r16[j];
    rr[2*j]   = make_float4(bl(q.x),bh(q.x),bl(q.y),bh(q.y));
    rr[2*j+1] = make_float4(bl(q.z),bh(q.z),bl(q.w),bh(q.w));
  }
}
__device__ __forceinline__ void store_row_l(unsigned* rp, const float4* rr){
  uint4* r16 = (uint4*)rp;
  #pragma unroll
  for (int j=0;j<8;++j){
    uint4 q;
    q.x = pk2(rr[2*j].x,   rr[2*j].y);
    q.y = pk2(rr[2*j].z,   rr[2*j].w);
    q.z = pk2(rr[2*j+1].x, rr[2*j+1].y);
    q.w = pk2(rr[2*j+1].z, rr[2*j+1].w);
    r16[j] = q;
  }
}

// logits tile (bf16 w_p, bf16 orow agent loads)
__device__ void logits_tile(const Params& p, int w, int tid, int tprev, float* ws){
  const unsigned* ob16 = p.orow16 + (size_t)(tprev&1)*BB*(PO/2);
  int cgl = w & 15, bg = w >> 4;
  int sub = tid >> 8, stid = tid & 255;
  int tb = stid >> 4, cq = stid & 15;
  int ar = tb, ac = cq << 2;
  int b0 = bg*16, col0 = cgl*64;
  float (*A_)[68]  = (float(*)[68])(ws + WS_GEMM_A);
  float (*Wt_)[68] = (float(*)[68])(ws + WS_GEMM_W);
  float (*Lc_)[68] = (float(*)[68])(ws + WS_GEMM_G);
  int c0 = cq*4;
  float acc0=0,acc1=0,acc2=0,acc3=0;
  uint2 aPre; uint4 wPre[2];
  const int NIT = 10;
  {
    int k0 = (0*2 + sub)*64;
    aPre = dloadu2(&ob16[((b0+ar)*PO + k0 + ac)>>1]);
    #pragma unroll
    for (int i2=0;i2<2;++i2){
      int li = i2*256 + stid; int ccl = li>>3; int kq = (stid&7)*8;
      wPre[i2] = *(const uint4*)&p.wp16[(size_t)(col0+ccl)*PO + k0 + kq];
    }
  }
  for (int it=0; it<NIT; ++it){
    A_[sub*16+ar][ac]=bl(aPre.x); A_[sub*16+ar][ac+1]=bh(aPre.x);
    A_[sub*16+ar][ac+2]=bl(aPre.y); A_[sub*16+ar][ac+3]=bh(aPre.y);
    #pragma unroll
    for (int i2=0;i2<2;++i2){
      int li = i2*256 + stid; int ccl = li>>3; int kq = (stid&7)*8;
      float f0=bl(wPre[i2].x),f1=bh(wPre[i2].x),f2=bl(wPre[i2].y),f3=bh(wPre[i2].y);
      float f4=bl(wPre[i2].z),f5=bh(wPre[i2].z),f6=bl(wPre[i2].w),f7=bh(wPre[i2].w);
      Wt_[sub*64+kq  ][ccl ^ ((((kq  )>>2)&7)<<2)] = f0;
      Wt_[sub*64+kq+1][ccl ^ ((((kq+1)>>2)&7)<<2)] = f1;
      Wt_[sub*64+kq+2][ccl ^ ((((kq+2)>>2)&7)<<2)] = f2;
      Wt_[sub*64+kq+3][ccl ^ ((((kq+3)>>2)&7)<<2)] = f3;
      Wt_[sub*64+kq+4][ccl ^ ((((kq+4)>>2)&7)<<2)] = f4;
      Wt_[sub*64+kq+5][ccl ^ ((((kq+5)>>2)&7)<<2)] = f5;
      Wt_[sub*64+kq+6][ccl ^ ((((kq+6)>>2)&7)<<2)] = f6;
      Wt_[sub*64+kq+7][ccl ^ ((((kq+7)>>2)&7)<<2)] = f7;
    }
    int nx = (it+1 < NIT) ? it+1 : it;
    {
      int k0 = (nx*2 + sub)*64;
      aPre = dloadu2(&ob16[((b0+ar)*PO + k0 + ac)>>1]);
      #pragma unroll
      for (int i2=0;i2<2;++i2){
        int li = i2*256 + stid; int ccl = li>>3; int kq = (stid&7)*8;
        wPre[i2] = *(const uint4*)&p.wp16[(size_t)(col0+ccl)*PO + k0 + kq];
      }
    }
    lds_barrier();
    #pragma unroll
    for (int kk=0;kk<16;++kk){
      float4 a4 = *(const float4*)&A_[sub*16+tb][kk*4];
      int cs = c0 ^ ((kk&7)<<2);
      float4 w0=*(const float4*)&Wt_[sub*64+kk*4  ][cs];
      float4 w1=*(const float4*)&Wt_[sub*64+kk*4+1][cs];
      float4 w2=*(const float4*)&Wt_[sub*64+kk*4+2][cs];
      float4 w3=*(const float4*)&Wt_[sub*64+kk*4+3][cs];
      acc0+=a4.x*w0.x; acc1+=a4.x*w0.y; acc2+=a4.x*w0.z; acc3+=a4.x*w0.w;
      acc0+=a4.y*w1.x; acc1+=a4.y*w1.y; acc2+=a4.y*w1.z; acc3+=a4.y*w1.w;
      acc0+=a4.z*w2.x; acc1+=a4.z*w2.y; acc2+=a4.z*w2.z; acc3+=a4.z*w2.w;
      acc0+=a4.w*w3.x; acc1+=a4.w*w3.y; acc2+=a4.w*w3.z; acc3+=a4.w*w3.w;
    }
    lds_barrier();
  }
  Lc_[sub*16+tb][c0]=acc0; Lc_[sub*16+tb][c0+1]=acc1;
  Lc_[sub*16+tb][c0+2]=acc2; Lc_[sub*16+tb][c0+3]=acc3;
  __syncthreads();
  if (tid < 256) {
    int tb2 = tid>>4, jl = tid&15;
    int cc0 = jl*4;
    int col = col0 + cc0;
    float4 o;
    o.x = Lc_[tb2][cc0]  +Lc_[16+tb2][cc0]   + p.b_p[col];
    o.y = Lc_[tb2][cc0+1]+Lc_[16+tb2][cc0+1] + p.b_p[col+1];
    o.z = Lc_[tb2][cc0+2]+Lc_[16+tb2][cc0+2] + p.b_p[col+2];
    o.w = Lc_[tb2][cc0+3]+Lc_[16+tb2][cc0+3] + p.b_p[col+3];
    *(float4*)&p.y[(size_t)((b0+tb2)*LL + tprev)*OO + col] = o;
  }
  __syncthreads();
}

__global__ __launch_bounds__(NT, 2) void dnc_all(Params p) {
  extern __shared__ unsigned dyn_lds[];
  unsigned* mrow = dyn_lds;
  float* ws = (float*)(dyn_lds + 512*MS);
  __shared__ float red[8];
  const int blk = blockIdx.x, tid = threadIdx.x;
  const int NB = gridDim.x;
  const int bP = blk >> 2, chP = blk & 3;
  const int wlog = ((bP & 1) << 3) | ((bP >> 1) & 7) | (bP & 48);
  unsigned bnum = 0;

  // ---------------- P0: init + bf16 weight conversion ----------------
  {
    int gidx = blk*NT + tid, gstr = NB*NT;
    for (int i = gidx; i < (4096*CIN)/2; i += gstr){
      float2 f = *(const float2*)&p.w_ih[2*(size_t)i];
      dstoreu((unsigned*)p.wih16 + i, pk2(f.x, f.y));
    }
    for (int i = gidx; i < (4096*HH)/2; i += gstr){
      float2 f = *(const float2*)&p.w_hh[2*(size_t)i];
      dstoreu((unsigned*)p.whh16 + i, pk2(f.x, f.y));
    }
    for (int i = gidx; i < (OO*PO)/2; i += gstr){
      float2 f = *(const float2*)&p.w_p[2*(size_t)i];
      dstoreu((unsigned*)p.wp16 + i, pk2(f.x, f.y));
    }
    for (int i = gidx; i < 449*512; i += gstr){
      int gr = i >> 9, kp = (i & 511)*2;
      const float* wrow = (gr<256)? p.w_rk + (size_t)gr*HH :
                          (gr<320)? p.w_wk + (size_t)(gr-256)*HH :
                          (gr==320)? p.w_ws :
                          (gr<385)? p.w_er + (size_t)(gr-321)*HH :
                                    p.w_ad + (size_t)(gr-385)*HH;
      dstoreu((unsigned*)p.whd16 + i, pk2(wrow[kp], wrow[kp+1]));
    }
    for (int i = tid; i < 512*MS; i += NT) mrow[i] = 0u;
    for (int i = gidx; i < (BB*HH)/2; i += gstr) dstoreu(&p.h16[i], 0u);
    if (blk < BB) {
      int b = blk;
      for (int i = tid; i < CIN; i += NT)
        ws[i] = (i < EE) ? p.x_emb[(size_t)(b*LL)*EE + i] : 0.f;
      __syncthreads();
      float s = 0.f;
      for (int i = tid; i < CIN; i += NT) s += ws[i];
      float mu = bsum(s, red) * (1.f/CIN);
      float ss = 0.f;
      for (int i = tid; i < CIN; i += NT) { float d = ws[i]-mu; ss += d*d; }
      float rstd = rsqrtf(bsum(ss, red)*(1.f/CIN) + EPSF);
      for (int i2 = tid; i2 < CIN/2; i2 += NT){
        float v0 = (ws[2*i2]-mu)*rstd*p.ln_in_g[2*i2] + p.ln_in_b[2*i2];
        float v1 = (ws[2*i2+1]-mu)*rstd*p.ln_in_g[2*i2+1] + p.ln_in_b[2*i2+1];
        dstoreu(&p.ci16[b*(CIN/2)+i2], pk2(v0, v1));
      }
    }
  }
  gbar(p.bar, ++bnum);

  for (int t = 0; t < LL; ++t) {
    const unsigned* hprev16 = p.h16 + (t & 1) * ((BB*HH)>>1);
    unsigned* hnew16 = p.h16 + ((t+1) & 1) * ((BB*HH)>>1);

    // -------- P1: gates GEMM + LSTM --------
    for (int w = blk; w < 256; w += NB) {
      int cgp = (w & 7) | (((w >> 3) & 7) << 3);
      int bg = w >> 6;
      int sub = tid >> 8, stid = tid & 255;
      int tb = stid >> 4, cq = stid & 15;
      int ar = tb, ac = cq << 2;
      int b0 = bg*16, j0 = cgp*16;
      float (*A_)[68]  = (float(*)[68])(ws + WS_GEMM_A);
      float (*Wt_)[68] = (float(*)[68])(ws + WS_GEMM_W);
      float (*Gv_)[68] = (float(*)[68])(ws + WS_GEMM_G);
      int c0 = cq*4;
      float acc0=0,acc1=0,acc2=0,acc3=0;
      uint2 aPre; uint4 wPre[2];
      const int NIT = 14;
      {
        int k0 = sub*64;
        aPre = dloadu2(&p.ci16[((b0+ar)*CIN + k0 + ac)>>1]);
        #pragma unroll
        for (int i2=0;i2<2;++i2){
          int li = i2*256 + stid; int ccl = li>>3; int kq = (stid&7)*8;
          int gate = ccl>>4, jl = ccl&15;
          wPre[i2] = *(const uint4*)&p.wih16[(size_t)(gate*HH + j0 + jl)*CIN + k0 + kq];
        }
      }
      for (int it=0; it<NIT; ++it){
        A_[sub*16+ar][ac]=bl(aPre.x); A_[sub*16+ar][ac+1]=bh(aPre.x);
        A_[sub*16+ar][ac+2]=bl(aPre.y); A_[sub*16+ar][ac+3]=bh(aPre.y);
        #pragma unroll
        for (int i2=0;i2<2;++i2){
          int li = i2*256 + stid; int ccl = li>>3; int kq = (stid&7)*8;
          float f0=bl(wPre[i2].x),f1=bh(wPre[i2].x),f2=bl(wPre[i2].y),f3=bh(wPre[i2].y);
          float f4=bl(wPre[i2].z),f5=bh(wPre[i2].z),f6=bl(wPre[i2].w),f7=bh(wPre[i2].w);
          Wt_[sub*64+kq  ][ccl ^ ((((kq  )>>2)&7)<<2)] = f0;
          Wt_[sub*64+kq+1][ccl ^ ((((kq+1)>>2)&7)<<2)] = f1;
          Wt_[sub*64+kq+2][ccl ^ ((((kq+2)>>2)&7)<<2)] = f2;
          Wt_[sub*64+kq+3][ccl ^ ((((kq+3)>>2)&7)<<2)] = f3;
          Wt_[sub*64+kq+4][ccl ^ ((((kq+4)>>2)&7)<<2)] = f4;
          Wt_[sub*64+kq+5][ccl ^ ((((kq+5)>>2)&7)<<2)] = f5;
          Wt_[sub*64+kq+6][ccl ^ ((((kq+6)>>2)&7)<<2)] = f6;
          Wt_[sub*64+kq+7][ccl ^ ((((kq+7)>>2)&7)<<2)] = f7;
        }
        int nx = (it+1 < NIT) ? it+1 : it;
        {
          const unsigned* As16; const unsigned short* Ws16; int K, k0;
          if (nx < 6){ As16 = p.ci16;  Ws16 = p.wih16; K = CIN; k0 = (nx*2 + sub)*64; }
          else       { As16 = hprev16; Ws16 = p.whh16; K = HH;  k0 = ((nx-6)*2 + sub)*64; }
          aPre = dloadu2(&As16[((b0+ar)*K + k0 + ac)>>1]);
          #pragma unroll
          for (int i2=0;i2<2;++i2){
            int li = i2*256 + stid; int ccl = li>>3; int kq = (stid&7)*8;
            int gate = ccl>>4, jl = ccl&15;
            wPre[i2] = *(const uint4*)&Ws16[(size_t)(gate*HH + j0 + jl)*K + k0 + kq];
          }
        }
        lds_barrier();
        #pragma unroll
        for (int kk=0;kk<16;++kk){
          float4 a4 = *(const float4*)&A_[sub*16+tb][kk*4];
          int cs = c0 ^ ((kk&7)<<2);
          float4 w0=*(const float4*)&Wt_[sub*64+kk*4  ][cs];
          float4 w1=*(const float4*)&Wt_[sub*64+kk*4+1][cs];
          float4 w2=*(const float4*)&Wt_[sub*64+kk*4+2][cs];
          float4 w3=*(const float4*)&Wt_[sub*64+kk*4+3][cs];
          acc0+=a4.x*w0.x; acc1+=a4.x*w0.y; acc2+=a4.x*w0.z; acc3+=a4.x*w0.w;
          acc0+=a4.y*w1.x; acc1+=a4.y*w1.y; acc2+=a4.y*w1.z; acc3+=a4.y*w1.w;
          acc0+=a4.z*w2.x; acc1+=a4.z*w2.y; acc2+=a4.z*w2.z; acc3+=a4.z*w2.w;
          acc0+=a4.w*w3.x; acc1+=a4.w*w3.y; acc2+=a4.w*w3.z; acc3+=a4.w*w3.w;
        }
        lds_barrier();
      }
      Gv_[sub*16+tb][c0]=acc0; Gv_[sub*16+tb][c0+1]=acc1;
      Gv_[sub*16+tb][c0+2]=acc2; Gv_[sub*16+tb][c0+3]=acc3;
      __syncthreads();
      if (tid < 256) {
        int tb2 = tid>>4, jl = tid&15;
        int r0 = 0*HH + j0 + jl, r1 = 1*HH + j0 + jl, r2 = 2*HH + j0 + jl, r3 = 3*HH + j0 + jl;
        float gi = Gv_[tb2][jl]    + Gv_[16+tb2][jl]    + p.b_ih[r0]+p.b_hh[r0];
        float gf = Gv_[tb2][16+jl] + Gv_[16+tb2][16+jl] + p.b_ih[r1]+p.b_hh[r1];
        float gg = Gv_[tb2][32+jl] + Gv_[16+tb2][32+jl] + p.b_ih[r2]+p.b_hh[r2];
        float go = Gv_[tb2][48+jl] + Gv_[16+tb2][48+jl] + p.b_ih[r3]+p.b_hh[r3];
        int idx3 = (b0+tb2)*HH + j0 + jl;
        float cold = (t==0) ? 0.f : p.c[idx3];
        float cn = sigm(gf)*cold + sigm(gi)*tanhf(gg);
        float hv = sigm(go)*tanhf(cn);
        p.c[idx3] = cn;
        float hvn = __shfl_down(hv, 1, 64);
        if ((tid & 1) == 0)
          dstoreu(&hnew16[idx3>>1], pk2(hv, hvn));
        if (t == LL-1) { p.ht[idx3] = hv; p.ct[idx3] = cn; }
      }
      __syncthreads();
    }
    gbar(p.bar, ++bnum);

    // -------- P2: hn LN + SPLIT heads GEMV (113 rows/block, 4 thr/row) --------
    {
      float* pHn = ws + WS_PHN;
      unsigned hu = dloadu(&hnew16[(bP*HH>>1) + tid]);
      float hx = bl(hu), hy = bh(hu);
      float s = bsum(hx + hy, red);
      float mu = s * (1.f/HH);
      float d0 = hx-mu, d1 = hy-mu;
      float ssq = bsum(d0*d0 + d1*d1, red);
      float rstd = rsqrtf(ssq*(1.f/HH)+EPSF);
      pHn[tid*2]   = d0*rstd*p.ln_c_g[tid*2]   + p.ln_c_b[tid*2];
      pHn[tid*2+1] = d1*rstd*p.ln_c_g[tid*2+1] + p.ln_c_b[tid*2+1];
      __syncthreads();
      int lr = tid >> 2, q = tid & 3;
      int base = chP*113;
      int cnt = (chP<3) ? 113 : 110;
      if (lr < cnt) {
        int gr = base + lr;
        const unsigned short* wr16 = p.whd16 + (size_t)gr*HH;
        float acc = 0.f;
        int k0 = q*256;
        #pragma unroll 4
        for (int k=k0; k<k0+256; k+=8){
          uint4 qd = *(const uint4*)&wr16[k];
          acc += bl(qd.x)*pHn[k  ] + bh(qd.x)*pHn[k+1] + bl(qd.y)*pHn[k+2] + bh(qd.y)*pHn[k+3]
               + bl(qd.z)*pHn[k+4] + bh(qd.z)*pHn[k+5] + bl(qd.w)*pHn[k+6] + bh(qd.w)*pHn[k+7];
        }
        acc += __shfl_down(acc, 1, 64);
        acc += __shfl_down(acc, 2, 64);
        if (q == 0) {
          float bias = (gr<256)? p.b_rk[gr] : (gr<320)? p.b_wk[gr-256] :
                       (gr==320)? p.b_ws[0] : (gr<385)? p.b_er[gr-321] : p.b_ad[gr-385];
          dstoref(&p.rawbuf[(size_t)bP*452 + gr], acc + bias);
        }
      }
    }
    gbar(p.bar, ++bnum);

    // -------- P3a: head LNs (from rawbuf) + pass A write-scores --------
    {
      float* bcg = ws + WS_BCG;
      float* raw = ws + WS_RAW;
      if (tid < 64) { bcg[tid] = p.ln_m_g[tid]; bcg[64+tid] = p.ln_m_b[tid]; }
      if (tid < 449) raw[tid] = dloadf(&p.rawbuf[(size_t)bP*452 + tid]);
      __syncthreads();
      if (tid < 256) {
        int l = tid & 63;
        float v = raw[tid];
        float sv=v; for(int o=32;o>0;o>>=1) sv += __shfl_xor(sv,o,64);
        float m2 = sv*(1.f/64.f);
        float d = v-m2; float sq=d*d;
        for(int o=32;o>0;o>>=1) sq += __shfl_xor(sq,o,64);
        float rs = rsqrtf(sq*(1.f/64.f)+EPSF);
        ws[WS_RKN + tid] = d*rs*p.ln_rk_g[l] + p.ln_rk_b[l];
      } else if (tid < 320) {
        int l = tid - 256;
        float v = raw[256+l];
        float sv=v; for(int o=32;o>0;o>>=1) sv += __shfl_xor(sv,o,64);
        float m2 = sv*(1.f/64.f);
        float d=v-m2; float sq=d*d;
        for(int o=32;o>0;o>>=1) sq += __shfl_xor(sq,o,64);
        float rs = rsqrtf(sq*(1.f/64.f)+EPSF);
        ws[WS_WKN + l] = d*rs*p.ln_wk_g[l] + p.ln_wk_b[l];
      } else if (tid < 384) {
        int l = tid - 320; ws[WS_ERS + l] = sigm(raw[321+l]);
      } else if (tid < 448) {
        int l = tid - 384; ws[WS_ADS + l] = tanhf(raw[385+l]);
      } else if (tid == 448) {
        ws[WS_WSS] = sigm(raw[320]);
      }
      __syncthreads();
      float4 rr[16];
      load_row_l(mrow + tid*MS, rr);
      float sc = row_score(rr, ws+WS_WKN, bcg, bcg+64);
      ws[WS_SW + tid] = sc;
      float mx = bmax(sc, red);
      float se = bsum(expf(sc-mx), red);
      if (tid==0){ dstoref(&p.wpart[(bP*4+chP)*2], mx); dstoref(&p.wpart[(bP*4+chP)*2+1], se); }
    }
    gbar(p.bar, ++bnum);

    // -------- P3b: mem update + read scores + chunk softmax + rv partials --------
    {
      float* bcg = ws + WS_BCG;
      float* srd = ws + WS_SRD;
      float* pRkn = ws + WS_RKN;
      float* pErs = ws + WS_ERS;
      float* pAds = ws + WS_ADS;
      float gmx = -3.4e38f, gsum = 0.f;
      #pragma unroll
      for (int cc=0; cc<4; ++cc) gmx = fmaxf(gmx, dloadf(&p.wpart[(bP*4+cc)*2]));
      #pragma unroll
      for (int cc=0; cc<4; ++cc)
        gsum += dloadf(&p.wpart[(bP*4+cc)*2+1]) * expf(dloadf(&p.wpart[(bP*4+cc)*2]) - gmx);
      float wstr = ws[WS_WSS];
      float ww = expf(ws[WS_SW + tid] - gmx)/gsum * wstr;
      unsigned* rp = mrow + tid*MS;
      float4 rr[16];
      load_row_l(rp, rr);
      #pragma unroll
      for (int i=0;i<16;++i){ int h=i*4;
        rr[i].x = rr[i].x*(1.f-ww*pErs[h  ]) + ww*pAds[h  ];
        rr[i].y = rr[i].y*(1.f-ww*pErs[h+1]) + ww*pAds[h+1];
        rr[i].z = rr[i].z*(1.f-ww*pErs[h+2]) + ww*pAds[h+2];
        rr[i].w = rr[i].w*(1.f-ww*pErs[h+3]) + ww*pAds[h+3];
      }
      store_row_l(rp, rr);
      float sum=0.f;
      #pragma unroll
      for (int i=0;i<16;++i) sum += rr[i].x+rr[i].y+rr[i].z+rr[i].w;
      float mu = sum*(1.f/64.f);
      float ssq=0.f;
      #pragma unroll
      for (int i=0;i<16;++i){ float dx=rr[i].x-mu,dy=rr[i].y-mu,dz=rr[i].z-mu,dw=rr[i].w-mu;
                              ssq+=dx*dx+dy*dy+dz*dz+dw*dw; }
      float rstd = rsqrtf(ssq*(1.f/64.f)+EPSF);
      float sN[4] = {0.f,0.f,0.f,0.f};
      #pragma unroll
      for (int i=0;i<16;++i){ int h=i*4;
        float n0=(rr[i].x-mu)*rstd*bcg[h  ]+bcg[64+h  ];
        float n1=(rr[i].y-mu)*rstd*bcg[h+1]+bcg[64+h+1];
        float n2=(rr[i].z-mu)*rstd*bcg[h+2]+bcg[64+h+2];
        float n3=(rr[i].w-mu)*rstd*bcg[h+3]+bcg[64+h+3];
        sN[0] += n0*pRkn[h    ]+n1*pRkn[h+1    ]+n2*pRkn[h+2    ]+n3*pRkn[h+3    ];
        sN[1] += n0*pRkn[64+h ]+n1*pRkn[64+h+1 ]+n2*pRkn[64+h+2 ]+n3*pRkn[64+h+3 ];
        sN[2] += n0*pRkn[128+h]+n1*pRkn[128+h+1]+n2*pRkn[128+h+2]+n3*pRkn[128+h+3];
        sN[3] += n0*pRkn[192+h]+n1*pRkn[192+h+1]+n2*pRkn[192+h+2]+n3*pRkn[192+h+3];
      }
      #pragma unroll
      for (int n=0;n<RR;++n){
        float mxn = bmax(sN[n], red);
        float sen = bsum(expf(sN[n]-mxn), red);
        srd[n*512 + tid] = expf(sN[n]-mxn);
        if (tid==0){
          dstoref(&p.rpart[(bP*4+chP)*8 + n*2], mxn);
          dstoref(&p.rpart[(bP*4+chP)*8 + n*2+1], sen);
        }
      }
      __syncthreads();
      int hs2 = (tid & 31) * 2, wg = tid >> 5;
      float a00=0,a01=0,a10=0,a11=0,a20=0,a21=0,a30=0,a31=0;
      for (int ml = wg; ml < 512; ml += 16){
        unsigned u = mrow[ml*MS + (hs2>>1)];
        float vlo = bl(u), vhi = bh(u);
        float w0 = srd[ml], w1 = srd[512+ml], w2 = srd[1024+ml], w3 = srd[1536+ml];
        a00 += w0*vlo; a01 += w0*vhi;
        a10 += w1*vlo; a11 += w1*vhi;
        a20 += w2*vlo; a21 += w2*vhi;
        a30 += w3*vlo; a31 += w3*vhi;
      }
      __syncthreads();
      float* part = ws + WS_PART;
      part[(0*16+wg)*64 + hs2] = a00; part[(0*16+wg)*64 + hs2+1] = a01;
      part[(1*16+wg)*64 + hs2] = a10; part[(1*16+wg)*64 + hs2+1] = a11;
      part[(2*16+wg)*64 + hs2] = a20; part[(2*16+wg)*64 + hs2+1] = a21;
      part[(3*16+wg)*64 + hs2] = a30; part[(3*16+wg)*64 + hs2+1] = a31;
      __syncthreads();
      if (tid < 256) {
        int n2 = tid>>6, h2 = tid&63;
        float v = 0.f;
        #pragma unroll
        for (int g2=0; g2<16; ++g2) v += part[(n2*16+g2)*64 + h2];
        dstoref(&p.rvpart[((bP*4+chP)*4 + n2)*64 + h2], v);
      }
    }
    gbar(p.bar, ++bnum);

    // -------- P4: rv combine + orow + ci (ch0) || logits(t-1) (ch1) --------
    if (chP == 0) {
      int b = bP;
      float* row   = ws + WS_ROW;
      float* cirow = ws + WS_CIROW;
      float* pHn   = ws + WS_PHN;
      if (tid < 256) {
        int n = tid>>6, h2 = tid&63;
        float gmxn = -3.4e38f;
        #pragma unroll
        for (int cc=0; cc<4; ++cc) gmxn = fmaxf(gmxn, dloadf(&p.rpart[(b*4+cc)*8 + n*2]));
        float den=0.f, num=0.f;
        #pragma unroll
        for (int cc=0; cc<4; ++cc){
          float e = expf(dloadf(&p.rpart[(b*4+cc)*8 + n*2]) - gmxn);
          den += dloadf(&p.rpart[(b*4+cc)*8 + n*2+1]) * e;
          num += dloadf(&p.rvpart[((b*4+cc)*4 + n)*64 + h2]) * e;
        }
        row[HH + tid] = num/den;
      }
      for (int i=tid;i<HH;i+=NT) row[i] = pHn[i];
      __syncthreads();
      float s=0.f; for (int i=tid;i<PO;i+=NT) s+=row[i];
      float mu = bsum(s,red)*(1.f/PO);
      float ss=0.f; for (int i=tid;i<PO;i+=NT){ float d=row[i]-mu; ss+=d*d; }
      float rstd = rsqrtf(bsum(ss,red)*(1.f/PO)+EPSF);
      unsigned* ob16 = p.orow16 + (size_t)(t&1)*BB*(PO/2);
      for (int i2=tid; i2<PO/2; i2+=NT){
        float v0 = (row[2*i2]-mu)*rstd*p.ln_o_g[2*i2]+p.ln_o_b[2*i2];
        float v1 = (row[2*i2+1]-mu)*rstd*p.ln_o_g[2*i2+1]+p.ln_o_b[2*i2+1];
        dstoreu(&ob16[b*(PO/2)+i2], pk2(v0, v1));
      }
      if (t+1 < LL) {
        for (int i=tid;i<CIN;i+=NT)
          cirow[i] = (i<EE)? p.x_emb[(size_t)(b*LL+t+1)*EE+i] : row[HH+(i-EE)];
        __syncthreads();
        float s2=0.f; for (int i=tid;i<CIN;i+=NT) s2+=cirow[i];
        float mu2 = bsum(s2,red)*(1.f/CIN);
        float ss2=0.f; for (int i=tid;i<CIN;i+=NT){ float d=cirow[i]-mu2; ss2+=d*d; }
        float rstd2 = rsqrtf(bsum(ss2,red)*(1.f/CIN)+EPSF);
        for (int i2=tid; i2<CIN/2; i2+=NT){
          float v0 = (cirow[2*i2]-mu2)*rstd2*p.ln_in_g[2*i2]+p.ln_in_b[2*i2];
          float v1 = (cirow[2*i2+1]-mu2)*rstd2*p.ln_in_g[2*i2+1]+p.ln_in_b[2*i2+1];
          dstoreu(&p.ci16[b*(CIN/2)+i2], pk2(v0, v1));
        }
      }
    } else if (chP == 1 && t > 0) {
      logits_tile(p, wlog, tid, t-1, ws);
    }
    gbar(p.bar, ++bnum);
  }

  // ---------------- finale: LDS mem -> fp32 memT + logits(255) ----------------
  {
    float* dst = p.mem + ((size_t)bP*MM + chP*CSL)*HSZ;
    int ml = tid;
    const uint4* src = (const uint4*)(mrow + ml*MS);
    float4* d4 = (float4*)(dst + (size_t)ml*HSZ);
    #pragma unroll
    for (int j=0;j<8;++j){
      uint4 q = src[j];
      d4[2*j]   = make_float4(bl(q.x),bh(q.x),bl(q.y),bh(q.y));
      d4[2*j+1] = make_float4(bl(q.z),bh(q.z),bl(q.w),bh(q.w));
    }
  }
  if (chP == 1) logits_tile(p, wlog, tid, LL-1, ws);
}

extern "C" void kernel_launch(void* const* d_in, const int* in_sizes, int n_in,
                              void* d_out, int out_size, void* d_ws, size_t ws_size,
                              hipStream_t stream) {
  Params prm;
  prm.x_emb  = (const float*)d_in[0];
  prm.ln_in_g= (const float*)d_in[1];
  prm.ln_in_b= (const float*)d_in[2];
  prm.w_ih   = (const float*)d_in[3];
  prm.w_hh   = (const float*)d_in[4];
  prm.b_ih   = (const float*)d_in[5];
  prm.b_hh   = (const float*)d_in[6];
  prm.ln_c_g = (const float*)d_in[7];
  prm.ln_c_b = (const float*)d_in[8];
  prm.w_rk   = (const float*)d_in[9];
  prm.b_rk   = (const float*)d_in[10];
  prm.w_wk   = (const float*)d_in[11];
  prm.b_wk   = (const float*)d_in[12];
  prm.w_ws   = (const float*)d_in[13];
  prm.b_ws   = (const float*)d_in[14];
  prm.w_er   = (const float*)d_in[15];
  prm.b_er   = (const float*)d_in[16];
  prm.w_ad   = (const float*)d_in[17];
  prm.b_ad   = (const float*)d_in[18];
  prm.ln_rk_g= (const float*)d_in[19];
  prm.ln_rk_b= (const float*)d_in[20];
  prm.ln_wk_g= (const float*)d_in[21];
  prm.ln_wk_b= (const float*)d_in[22];
  prm.ln_m_g = (const float*)d_in[23];
  prm.ln_m_b = (const float*)d_in[24];
  prm.ln_o_g = (const float*)d_in[25];
  prm.ln_o_b = (const float*)d_in[26];
  prm.w_p    = (const float*)d_in[27];
  prm.b_p    = (const float*)d_in[28];

  float* out = (float*)d_out;
  prm.y   = out + OUT_Y;
  prm.mem = out + OUT_MEM;
  prm.ht  = out + OUT_HT;
  prm.ct  = out + OUT_CT;

  prm.bar = (unsigned*)d_ws;
  hipMemsetAsync(d_ws, 0, 4096, stream);

  float* ws = (float*)((char*)d_ws + 4096);
  size_t o = 0;
  prm.c      = ws + o; o += BB*HH;
  prm.h16    = (unsigned*)(ws + o); o += BB*HH;
  prm.ci16   = (unsigned*)(ws + o); o += (BB*CIN)/2;
  prm.orow16 = (unsigned*)(ws + o); o += BB*PO;
  prm.wpart  = ws + o; o += 256*2;
  prm.rpart  = ws + o; o += 256*8;
  prm.rvpart = ws + o; o += 256*4*64;
  prm.rawbuf = ws + o; o += BB*452;
  prm.wih16  = (unsigned short*)(ws + o); o += (4096*CIN)/2;
  prm.whh16  = (unsigned short*)(ws + o); o += (4096*HH)/2;
  prm.wp16   = (unsigned short*)(ws + o); o += (OO*PO)/2;
  prm.whd16  = (unsigned short*)(ws + o); o += (449*HH)/2 + 64;

  hipFuncSetAttribute((const void*)dnc_all,
                      hipFuncAttributeMaxDynamicSharedMemorySize, DYN_BYTES);

  dnc_all<<<dim3(NB_REQ), dim3(NT), DYN_BYTES, stream>>>(prm);
}

// Round 17
// 27049.252 us; speedup vs baseline: 1.2955x; 1.0061x over previous
//
#include <hip/hip_runtime.h>
#include <math.h>

#define BB 64
#define LL 256
#define EE 512
#define HH 1024
#define MM 2048
#define HSZ 64
#define RR 4
#define CIN 768
#define PO 1280
#define OO 1024
#define EPSF 1e-5f
#define NT 512
#define NB_REQ 256
#define MS 36
#define CSL 512

// ---- d_out layout (float offsets) ----
#define OUT_Y    0
#define OUT_MEM  (BB * LL * OO)
#define OUT_HT   (OUT_MEM + BB * MM * HSZ)
#define OUT_CT   (OUT_HT + BB * HH)

// ---- workspace (float offsets inside ws = dyn_lds after mem region) ----
#define WS_RAW   0
#define WS_SW    512
#define WS_SRD   1024
#define WS_BCG   3072
#define WS_PHN   3200
#define WS_RKN   4224
#define WS_WKN   4480
#define WS_ERS   4544
#define WS_ADS   4608
#define WS_WSS   4672
#define WS_PART  5120
#define WS_ROW   5120
#define WS_CIROW 6400
#define WS_HREP  5120          // P2 only: 4 staggered pHn copies, stride 1032
#define WS_GEMM_A  0
#define WS_GEMM_W  2176
#define WS_GEMM_G  10880
#define WS_FLOATS  13056
#define DYN_BYTES ((512*MS + WS_FLOATS) * 4)

struct Params {
  const float *x_emb, *ln_in_g, *ln_in_b, *w_ih, *w_hh, *b_ih, *b_hh;
  const float *ln_c_g, *ln_c_b, *w_rk, *b_rk, *w_wk, *b_wk, *w_ws, *b_ws;
  const float *w_er, *b_er, *w_ad, *b_ad, *ln_rk_g, *ln_rk_b, *ln_wk_g, *ln_wk_b;
  const float *ln_m_g, *ln_m_b, *ln_o_g, *ln_o_b, *w_p, *b_p;
  float *y, *mem, *ht, *ct;
  float *c, *wpart, *rpart, *rvpart, *rawbuf;
  unsigned *h16, *ci16, *orow16;
  unsigned short *wih16, *whh16, *wp16, *whd16;
  unsigned *bar;
};

__device__ __forceinline__ float sigm(float x){ return 1.f/(1.f+expf(-x)); }
__device__ __forceinline__ float bl(unsigned u){ return __uint_as_float(u<<16); }
__device__ __forceinline__ float bh(unsigned u){ return __uint_as_float(u & 0xffff0000u); }
__device__ __forceinline__ unsigned pk2(float a, float b){
  unsigned ua = __float_as_uint(a), ub = __float_as_uint(b);
  ua = (ua + 0x7fffu + ((ua>>16)&1u)) >> 16;
  ub = (ub + 0x7fffu + ((ub>>16)&1u)) >> 16;
  return ua | (ub<<16);
}

__device__ __forceinline__ unsigned dloadu(const unsigned* p){
  return __hip_atomic_load(p, __ATOMIC_RELAXED, __HIP_MEMORY_SCOPE_AGENT);
}
__device__ __forceinline__ uint2 dloadu2(const unsigned* p){
  unsigned long long u = __hip_atomic_load((const unsigned long long*)p,
                                           __ATOMIC_RELAXED, __HIP_MEMORY_SCOPE_AGENT);
  uint2 r; r.x = (unsigned)(u & 0xffffffffull); r.y = (unsigned)(u >> 32); return r;
}
__device__ __forceinline__ void dstoreu(unsigned* p, unsigned v){
  __hip_atomic_store(p, v, __ATOMIC_RELAXED, __HIP_MEMORY_SCOPE_AGENT);
}
__device__ __forceinline__ float dloadf(const float* p){
  return __hip_atomic_load(p, __ATOMIC_RELAXED, __HIP_MEMORY_SCOPE_AGENT);
}
__device__ __forceinline__ void dstoref(float* p, float v){
  __hip_atomic_store(p, v, __ATOMIC_RELAXED, __HIP_MEMORY_SCOPE_AGENT);
}

__device__ __forceinline__ void lds_barrier() {
  asm volatile("s_waitcnt lgkmcnt(0)" ::: "memory");
  __builtin_amdgcn_sched_barrier(0);
  __builtin_amdgcn_s_barrier();
  __builtin_amdgcn_sched_barrier(0);
}

// 2-level tree grid barrier: 16 leaves x 16 blocks, all counters on own 64B lines.
__device__ __forceinline__ void gbar(unsigned* bar, unsigned bnum) {
  __syncthreads();
  if (threadIdx.x == 0) {
    asm volatile("s_waitcnt vmcnt(0)" ::: "memory");
    int g = blockIdx.x & 15;
    unsigned a = __hip_atomic_fetch_add(&bar[16 + g*16], 1u,
                    __ATOMIC_RELAXED, __HIP_MEMORY_SCOPE_AGENT) + 1u;
    if (a == bnum * 16u) {
      unsigned r = __hip_atomic_fetch_add(&bar[0], 1u,
                      __ATOMIC_RELAXED, __HIP_MEMORY_SCOPE_AGENT) + 1u;
      if (r == bnum * 16u) {
        #pragma unroll
        for (int i=0;i<16;++i)
          __hip_atomic_fetch_add(&bar[512 + i*16], 1u,
                                 __ATOMIC_RELAXED, __HIP_MEMORY_SCOPE_AGENT);
      }
    }
    while (__hip_atomic_load(&bar[512 + g*16], __ATOMIC_RELAXED,
                             __HIP_MEMORY_SCOPE_AGENT) < bnum) {
      __builtin_amdgcn_s_sleep(8);
    }
    asm volatile("" ::: "memory");
  }
  __syncthreads();
}

__device__ __forceinline__ float bsum(float v, volatile float* red){
  __syncthreads();
  for (int o=32;o>0;o>>=1) v += __shfl_down(v,o,64);
  int w = threadIdx.x>>6;
  if ((threadIdx.x&63)==0) red[w]=v;
  __syncthreads();
  return red[0]+red[1]+red[2]+red[3]+red[4]+red[5]+red[6]+red[7];
}
__device__ __forceinline__ float bmax(float v, volatile float* red){
  __syncthreads();
  for (int o=32;o>0;o>>=1) v = fmaxf(v,__shfl_down(v,o,64));
  int w = threadIdx.x>>6;
  if ((threadIdx.x&63)==0) red[w]=v;
  __syncthreads();
  float a = fmaxf(fmaxf(red[0],red[1]),fmaxf(red[2],red[3]));
  float b = fmaxf(fmaxf(red[4],red[5]),fmaxf(red[6],red[7]));
  return fmaxf(a,b);
}

__device__ __forceinline__ float row_score(const float4* v, const float* wk,
                                           const float* g, const float* bt){
  float sum=0.f;
  #pragma unroll
  for (int i=0;i<16;++i) sum += v[i].x+v[i].y+v[i].z+v[i].w;
  float mu = sum*(1.f/64.f);
  float ssq=0.f;
  #pragma unroll
  for (int i=0;i<16;++i){ float dx=v[i].x-mu,dy=v[i].y-mu,dz=v[i].z-mu,dw=v[i].w-mu;
                          ssq+=dx*dx+dy*dy+dz*dz+dw*dw; }
  float rstd = rsqrtf(ssq*(1.f/64.f)+EPSF);
  float sc=0.f;
  #pragma unroll
  for (int i=0;i<16;++i){ int h=i*4;
    sc += ((v[i].x-mu)*rstd*g[h  ]+bt[h  ])*wk[h  ];
    sc += ((v[i].y-mu)*rstd*g[h+1]+bt[h+1])*wk[h+1];
    sc += ((v[i].z-mu)*rstd*g[h+2]+bt[h+2])*wk[h+2];
    sc += ((v[i].w-mu)*rstd*g[h+3]+bt[h+3])*wk[h+3];
  }
  return sc;
}

__device__ __forceinline__ void load_row_l(const unsigned* rp, float4* rr){
  const uint4* r16 = (const uint4*)rp;
  #pragma unroll
  for (int j=0;j<8;++j){
    uint4 q = r16[j];
    rr[2*j]   = make_float4(bl(q.x),bh(q.x),bl(q.y),bh(q.y));
    rr[2*j+1] = make_float4(bl(q.z),bh(q.z),bl(q.w),bh(q.w));
  }
}
__device__ __forceinline__ void store_row_l(unsigned* rp, const float4* rr){
  uint4* r16 = (uint4*)rp;
  #pragma unroll
  for (int j=0;j<8;++j){
    uint4 q;
    q.x = pk2(rr[2*j].x,   rr[2*j].y);
    q.y = pk2(rr[2*j].z,   rr[2*j].w);
    q.z = pk2(rr[2*j+1].x, rr[2*j+1].y);
    q.w = pk2(rr[2*j+1].z, rr[2*j+1].w);
    r16[j] = q;
  }
}

// logits tile (bf16 w_p, bf16 orow agent loads)
__device__ void logits_tile(const Params& p, int w, int tid, int tprev, float* ws){
  const unsigned* ob16 = p.orow16 + (size_t)(tprev&1)*BB*(PO/2);
  int cgl = w & 15, bg = w >> 4;
  int sub = tid >> 8, stid = tid & 255;
  int tb = stid >> 4, cq = stid & 15;
  int ar = tb, ac = cq << 2;
  int b0 = bg*16, col0 = cgl*64;
  float (*A_)[68]  = (float(*)[68])(ws + WS_GEMM_A);
  float (*Wt_)[68] = (float(*)[68])(ws + WS_GEMM_W);
  float (*Lc_)[68] = (float(*)[68])(ws + WS_GEMM_G);
  int c0 = cq*4;
  float acc0=0,acc1=0,acc2=0,acc3=0;
  uint2 aPre; uint4 wPre[2];
  const int NIT = 10;
  {
    int k0 = (0*2 + sub)*64;
    aPre = dloadu2(&ob16[((b0+ar)*PO + k0 + ac)>>1]);
    #pragma unroll
    for (int i2=0;i2<2;++i2){
      int li = i2*256 + stid; int ccl = li>>3; int kq = (stid&7)*8;
      wPre[i2] = *(const uint4*)&p.wp16[(size_t)(col0+ccl)*PO + k0 + kq];
    }
  }
  for (int it=0; it<NIT; ++it){
    A_[sub*16+ar][ac]=bl(aPre.x); A_[sub*16+ar][ac+1]=bh(aPre.x);
    A_[sub*16+ar][ac+2]=bl(aPre.y); A_[sub*16+ar][ac+3]=bh(aPre.y);
    #pragma unroll
    for (int i2=0;i2<2;++i2){
      int li = i2*256 + stid; int ccl = li>>3; int kq = (stid&7)*8;
      float f0=bl(wPre[i2].x),f1=bh(wPre[i2].x),f2=bl(wPre[i2].y),f3=bh(wPre[i2].y);
      float f4=bl(wPre[i2].z),f5=bh(wPre[i2].z),f6=bl(wPre[i2].w),f7=bh(wPre[i2].w);
      Wt_[sub*64+kq  ][ccl ^ ((((kq  )>>2)&7)<<2)] = f0;
      Wt_[sub*64+kq+1][ccl ^ ((((kq+1)>>2)&7)<<2)] = f1;
      Wt_[sub*64+kq+2][ccl ^ ((((kq+2)>>2)&7)<<2)] = f2;
      Wt_[sub*64+kq+3][ccl ^ ((((kq+3)>>2)&7)<<2)] = f3;
      Wt_[sub*64+kq+4][ccl ^ ((((kq+4)>>2)&7)<<2)] = f4;
      Wt_[sub*64+kq+5][ccl ^ ((((kq+5)>>2)&7)<<2)] = f5;
      Wt_[sub*64+kq+6][ccl ^ ((((kq+6)>>2)&7)<<2)] = f6;
      Wt_[sub*64+kq+7][ccl ^ ((((kq+7)>>2)&7)<<2)] = f7;
    }
    int nx = (it+1 < NIT) ? it+1 : it;
    {
      int k0 = (nx*2 + sub)*64;
      aPre = dloadu2(&ob16[((b0+ar)*PO + k0 + ac)>>1]);
      #pragma unroll
      for (int i2=0;i2<2;++i2){
        int li = i2*256 + stid; int ccl = li>>3; int kq = (stid&7)*8;
        wPre[i2] = *(const uint4*)&p.wp16[(size_t)(col0+ccl)*PO + k0 + kq];
      }
    }
    lds_barrier();
    #pragma unroll
    for (int kk=0;kk<16;++kk){
      float4 a4 = *(const float4*)&A_[sub*16+tb][kk*4];
      int cs = c0 ^ ((kk&7)<<2);
      float4 w0=*(const float4*)&Wt_[sub*64+kk*4  ][cs];
      float4 w1=*(const float4*)&Wt_[sub*64+kk*4+1][cs];
      float4 w2=*(const float4*)&Wt_[sub*64+kk*4+2][cs];
      float4 w3=*(const float4*)&Wt_[sub*64+kk*4+3][cs];
      acc0+=a4.x*w0.x; acc1+=a4.x*w0.y; acc2+=a4.x*w0.z; acc3+=a4.x*w0.w;
      acc0+=a4.y*w1.x; acc1+=a4.y*w1.y; acc2+=a4.y*w1.z; acc3+=a4.y*w1.w;
      acc0+=a4.z*w2.x; acc1+=a4.z*w2.y; acc2+=a4.z*w2.z; acc3+=a4.z*w2.w;
      acc0+=a4.w*w3.x; acc1+=a4.w*w3.y; acc2+=a4.w*w3.z; acc3+=a4.w*w3.w;
    }
    lds_barrier();
  }
  Lc_[sub*16+tb][c0]=acc0; Lc_[sub*16+tb][c0+1]=acc1;
  Lc_[sub*16+tb][c0+2]=acc2; Lc_[sub*16+tb][c0+3]=acc3;
  __syncthreads();
  if (tid < 256) {
    int tb2 = tid>>4, jl = tid&15;
    int cc0 = jl*4;
    int col = col0 + cc0;
    float4 o;
    o.x = Lc_[tb2][cc0]  +Lc_[16+tb2][cc0]   + p.b_p[col];
    o.y = Lc_[tb2][cc0+1]+Lc_[16+tb2][cc0+1] + p.b_p[col+1];
    o.z = Lc_[tb2][cc0+2]+Lc_[16+tb2][cc0+2] + p.b_p[col+2];
    o.w = Lc_[tb2][cc0+3]+Lc_[16+tb2][cc0+3] + p.b_p[col+3];
    *(float4*)&p.y[(size_t)((b0+tb2)*LL + tprev)*OO + col] = o;
  }
  __syncthreads();
}

__global__ __launch_bounds__(NT, 2) void dnc_all(Params p) {
  extern __shared__ unsigned dyn_lds[];
  unsigned* mrow = dyn_lds;
  float* ws = (float*)(dyn_lds + 512*MS);
  __shared__ float red[8];
  const int blk = blockIdx.x, tid = threadIdx.x;
  const int NB = gridDim.x;
  const int bP = blk >> 2, chP = blk & 3;
  const int wlog = ((bP & 1) << 3) | ((bP >> 1) & 7) | (bP & 48);
  unsigned bnum = 0;

  // ---------------- P0: init + bf16 weight conversion ----------------
  {
    int gidx = blk*NT + tid, gstr = NB*NT;
    for (int i = gidx; i < (4096*CIN)/2; i += gstr){
      float2 f = *(const float2*)&p.w_ih[2*(size_t)i];
      dstoreu((unsigned*)p.wih16 + i, pk2(f.x, f.y));
    }
    for (int i = gidx; i < (4096*HH)/2; i += gstr){
      float2 f = *(const float2*)&p.w_hh[2*(size_t)i];
      dstoreu((unsigned*)p.whh16 + i, pk2(f.x, f.y));
    }
    for (int i = gidx; i < (OO*PO)/2; i += gstr){
      float2 f = *(const float2*)&p.w_p[2*(size_t)i];
      dstoreu((unsigned*)p.wp16 + i, pk2(f.x, f.y));
    }
    for (int i = gidx; i < 449*512; i += gstr){
      int gr = i >> 9, kp = (i & 511)*2;
      const float* wrow = (gr<256)? p.w_rk + (size_t)gr*HH :
                          (gr<320)? p.w_wk + (size_t)(gr-256)*HH :
                          (gr==320)? p.w_ws :
                          (gr<385)? p.w_er + (size_t)(gr-321)*HH :
                                    p.w_ad + (size_t)(gr-385)*HH;
      dstoreu((unsigned*)p.whd16 + i, pk2(wrow[kp], wrow[kp+1]));
    }
    for (int i = tid; i < 512*MS; i += NT) mrow[i] = 0u;
    for (int i = gidx; i < (BB*HH)/2; i += gstr) dstoreu(&p.h16[i], 0u);
    if (blk < BB) {
      int b = blk;
      for (int i = tid; i < CIN; i += NT)
        ws[i] = (i < EE) ? p.x_emb[(size_t)(b*LL)*EE + i] : 0.f;
      __syncthreads();
      float s = 0.f;
      for (int i = tid; i < CIN; i += NT) s += ws[i];
      float mu = bsum(s, red) * (1.f/CIN);
      float ss = 0.f;
      for (int i = tid; i < CIN; i += NT) { float d = ws[i]-mu; ss += d*d; }
      float rstd = rsqrtf(bsum(ss, red)*(1.f/CIN) + EPSF);
      for (int i2 = tid; i2 < CIN/2; i2 += NT){
        float v0 = (ws[2*i2]-mu)*rstd*p.ln_in_g[2*i2] + p.ln_in_b[2*i2];
        float v1 = (ws[2*i2+1]-mu)*rstd*p.ln_in_g[2*i2+1] + p.ln_in_b[2*i2+1];
        dstoreu(&p.ci16[b*(CIN/2)+i2], pk2(v0, v1));
      }
    }
  }
  gbar(p.bar, ++bnum);

  for (int t = 0; t < LL; ++t) {
    const unsigned* hprev16 = p.h16 + (t & 1) * ((BB*HH)>>1);
    unsigned* hnew16 = p.h16 + ((t+1) & 1) * ((BB*HH)>>1);

    // -------- P1: gates GEMM + LSTM --------
    for (int w = blk; w < 256; w += NB) {
      int cgp = (w & 7) | (((w >> 3) & 7) << 3);
      int bg = w >> 6;
      int sub = tid >> 8, stid = tid & 255;
      int tb = stid >> 4, cq = stid & 15;
      int ar = tb, ac = cq << 2;
      int b0 = bg*16, j0 = cgp*16;
      float (*A_)[68]  = (float(*)[68])(ws + WS_GEMM_A);
      float (*Wt_)[68] = (float(*)[68])(ws + WS_GEMM_W);
      float (*Gv_)[68] = (float(*)[68])(ws + WS_GEMM_G);
      int c0 = cq*4;
      float acc0=0,acc1=0,acc2=0,acc3=0;
      uint2 aPre; uint4 wPre[2];
      const int NIT = 14;
      {
        int k0 = sub*64;
        aPre = dloadu2(&p.ci16[((b0+ar)*CIN + k0 + ac)>>1]);
        #pragma unroll
        for (int i2=0;i2<2;++i2){
          int li = i2*256 + stid; int ccl = li>>3; int kq = (stid&7)*8;
          int gate = ccl>>4, jl = ccl&15;
          wPre[i2] = *(const uint4*)&p.wih16[(size_t)(gate*HH + j0 + jl)*CIN + k0 + kq];
        }
      }
      for (int it=0; it<NIT; ++it){
        A_[sub*16+ar][ac]=bl(aPre.x); A_[sub*16+ar][ac+1]=bh(aPre.x);
        A_[sub*16+ar][ac+2]=bl(aPre.y); A_[sub*16+ar][ac+3]=bh(aPre.y);
        #pragma unroll
        for (int i2=0;i2<2;++i2){
          int li = i2*256 + stid; int ccl = li>>3; int kq = (stid&7)*8;
          float f0=bl(wPre[i2].x),f1=bh(wPre[i2].x),f2=bl(wPre[i2].y),f3=bh(wPre[i2].y);
          float f4=bl(wPre[i2].z),f5=bh(wPre[i2].z),f6=bl(wPre[i2].w),f7=bh(wPre[i2].w);
          Wt_[sub*64+kq  ][ccl ^ ((((kq  )>>2)&7)<<2)] = f0;
          Wt_[sub*64+kq+1][ccl ^ ((((kq+1)>>2)&7)<<2)] = f1;
          Wt_[sub*64+kq+2][ccl ^ ((((kq+2)>>2)&7)<<2)] = f2;
          Wt_[sub*64+kq+3][ccl ^ ((((kq+3)>>2)&7)<<2)] = f3;
          Wt_[sub*64+kq+4][ccl ^ ((((kq+4)>>2)&7)<<2)] = f4;
          Wt_[sub*64+kq+5][ccl ^ ((((kq+5)>>2)&7)<<2)] = f5;
          Wt_[sub*64+kq+6][ccl ^ ((((kq+6)>>2)&7)<<2)] = f6;
          Wt_[sub*64+kq+7][ccl ^ ((((kq+7)>>2)&7)<<2)] = f7;
        }
        int nx = (it+1 < NIT) ? it+1 : it;
        {
          const unsigned* As16; const unsigned short* Ws16; int K, k0;
          if (nx < 6){ As16 = p.ci16;  Ws16 = p.wih16; K = CIN; k0 = (nx*2 + sub)*64; }
          else       { As16 = hprev16; Ws16 = p.whh16; K = HH;  k0 = ((nx-6)*2 + sub)*64; }
          aPre = dloadu2(&As16[((b0+ar)*K + k0 + ac)>>1]);
          #pragma unroll
          for (int i2=0;i2<2;++i2){
            int li = i2*256 + stid; int ccl = li>>3; int kq = (stid&7)*8;
            int gate = ccl>>4, jl = ccl&15;
            wPre[i2] = *(const uint4*)&Ws16[(size_t)(gate*HH + j0 + jl)*K + k0 + kq];
          }
        }
        lds_barrier();
        #pragma unroll
        for (int kk=0;kk<16;++kk){
          float4 a4 = *(const float4*)&A_[sub*16+tb][kk*4];
          int cs = c0 ^ ((kk&7)<<2);
          float4 w0=*(const float4*)&Wt_[sub*64+kk*4  ][cs];
          float4 w1=*(const float4*)&Wt_[sub*64+kk*4+1][cs];
          float4 w2=*(const float4*)&Wt_[sub*64+kk*4+2][cs];
          float4 w3=*(const float4*)&Wt_[sub*64+kk*4+3][cs];
          acc0+=a4.x*w0.x; acc1+=a4.x*w0.y; acc2+=a4.x*w0.z; acc3+=a4.x*w0.w;
          acc0+=a4.y*w1.x; acc1+=a4.y*w1.y; acc2+=a4.y*w1.z; acc3+=a4.y*w1.w;
          acc0+=a4.z*w2.x; acc1+=a4.z*w2.y; acc2+=a4.z*w2.z; acc3+=a4.z*w2.w;
          acc0+=a4.w*w3.x; acc1+=a4.w*w3.y; acc2+=a4.w*w3.z; acc3+=a4.w*w3.w;
        }
        lds_barrier();
      }
      Gv_[sub*16+tb][c0]=acc0; Gv_[sub*16+tb][c0+1]=acc1;
      Gv_[sub*16+tb][c0+2]=acc2; Gv_[sub*16+tb][c0+3]=acc3;
      __syncthreads();
      if (tid < 256) {
        int tb2 = tid>>4, jl = tid&15;
        int r0 = 0*HH + j0 + jl, r1 = 1*HH + j0 + jl, r2 = 2*HH + j0 + jl, r3 = 3*HH + j0 + jl;
        float gi = Gv_[tb2][jl]    + Gv_[16+tb2][jl]    + p.b_ih[r0]+p.b_hh[r0];
        float gf = Gv_[tb2][16+jl] + Gv_[16+tb2][16+jl] + p.b_ih[r1]+p.b_hh[r1];
        float gg = Gv_[tb2][32+jl] + Gv_[16+tb2][32+jl] + p.b_ih[r2]+p.b_hh[r2];
        float go = Gv_[tb2][48+jl] + Gv_[16+tb2][48+jl] + p.b_ih[r3]+p.b_hh[r3];
        int idx3 = (b0+tb2)*HH + j0 + jl;
        float cold = (t==0) ? 0.f : p.c[idx3];
        float cn = sigm(gf)*cold + sigm(gi)*tanhf(gg);
        float hv = sigm(go)*tanhf(cn);
        p.c[idx3] = cn;
        float hvn = __shfl_down(hv, 1, 64);
        if ((tid & 1) == 0)
          dstoreu(&hnew16[idx3>>1], pk2(hv, hvn));
        if (t == LL-1) { p.ht[idx3] = hv; p.ct[idx3] = cn; }
      }
      __syncthreads();
    }
    gbar(p.bar, ++bnum);

    // -------- P2: hn LN + SPLIT heads GEMV (4x staggered pHn copies) --------
    {
      float* pHn = ws + WS_PHN;
      unsigned hu = dloadu(&hnew16[(bP*HH>>1) + tid]);
      float hx = bl(hu), hy = bh(hu);
      float s = bsum(hx + hy, red);
      float mu = s * (1.f/HH);
      float d0 = hx-mu, d1 = hy-mu;
      float ssq = bsum(d0*d0 + d1*d1, red);
      float rstd = rsqrtf(ssq*(1.f/HH)+EPSF);
      float v0 = d0*rstd*p.ln_c_g[tid*2]   + p.ln_c_b[tid*2];
      float v1 = d1*rstd*p.ln_c_g[tid*2+1] + p.ln_c_b[tid*2+1];
      pHn[tid*2] = v0; pHn[tid*2+1] = v1;
      // 4 staggered copies (stride 1032 floats -> bank offset 8 per copy):
      // quarter q's readers broadcast one address within disjoint bank-quads.
      #pragma unroll
      for (int q=0;q<4;++q){
        float* cp = ws + WS_HREP + q*1032;
        cp[tid*2] = v0; cp[tid*2+1] = v1;
      }
      __syncthreads();
      int lr = tid >> 2, q = tid & 3;
      int base = chP*113;
      int cnt = (chP<3) ? 113 : 110;
      if (lr < cnt) {
        int gr = base + lr;
        const unsigned short* wr16 = p.whd16 + (size_t)gr*HH;
        const float* hb = ws + WS_HREP + q*1032;
        float acc = 0.f;
        int k0 = q*256;
        #pragma unroll 4
        for (int k=k0; k<k0+256; k+=8){
          uint4 qd = *(const uint4*)&wr16[k];
          float4 h0 = *(const float4*)&hb[k];
          float4 h1 = *(const float4*)&hb[k+4];
          acc += bl(qd.x)*h0.x + bh(qd.x)*h0.y + bl(qd.y)*h0.z + bh(qd.y)*h0.w
               + bl(qd.z)*h1.x + bh(qd.z)*h1.y + bl(qd.w)*h1.z + bh(qd.w)*h1.w;
        }
        acc += __shfl_down(acc, 1, 64);
        acc += __shfl_down(acc, 2, 64);
        if (q == 0) {
          float bias = (gr<256)? p.b_rk[gr] : (gr<320)? p.b_wk[gr-256] :
                       (gr==320)? p.b_ws[0] : (gr<385)? p.b_er[gr-321] : p.b_ad[gr-385];
          dstoref(&p.rawbuf[(size_t)bP*452 + gr], acc + bias);
        }
      }
    }
    gbar(p.bar, ++bnum);

    // -------- P3a: head LNs (from rawbuf) + pass A write-scores --------
    {
      float* bcg = ws + WS_BCG;
      float* raw = ws + WS_RAW;
      if (tid < 64) { bcg[tid] = p.ln_m_g[tid]; bcg[64+tid] = p.ln_m_b[tid]; }
      if (tid < 449) raw[tid] = dloadf(&p.rawbuf[(size_t)bP*452 + tid]);
      __syncthreads();
      if (tid < 256) {
        int l = tid & 63;
        float v = raw[tid];
        float sv=v; for(int o=32;o>0;o>>=1) sv += __shfl_xor(sv,o,64);
        float m2 = sv*(1.f/64.f);
        float d = v-m2; float sq=d*d;
        for(int o=32;o>0;o>>=1) sq += __shfl_xor(sq,o,64);
        float rs = rsqrtf(sq*(1.f/64.f)+EPSF);
        ws[WS_RKN + tid] = d*rs*p.ln_rk_g[l] + p.ln_rk_b[l];
      } else if (tid < 320) {
        int l = tid - 256;
        float v = raw[256+l];
        float sv=v; for(int o=32;o>0;o>>=1) sv += __shfl_xor(sv,o,64);
        float m2 = sv*(1.f/64.f);
        float d=v-m2; float sq=d*d;
        for(int o=32;o>0;o>>=1) sq += __shfl_xor(sq,o,64);
        float rs = rsqrtf(sq*(1.f/64.f)+EPSF);
        ws[WS_WKN + l] = d*rs*p.ln_wk_g[l] + p.ln_wk_b[l];
      } else if (tid < 384) {
        int l = tid - 320; ws[WS_ERS + l] = sigm(raw[321+l]);
      } else if (tid < 448) {
        int l = tid - 384; ws[WS_ADS + l] = tanhf(raw[385+l]);
      } else if (tid == 448) {
        ws[WS_WSS] = sigm(raw[320]);
      }
      __syncthreads();
      float4 rr[16];
      load_row_l(mrow + tid*MS, rr);
      float sc = row_score(rr, ws+WS_WKN, bcg, bcg+64);
      ws[WS_SW + tid] = sc;
      float mx = bmax(sc, red);
      float se = bsum(expf(sc-mx), red);
      if (tid==0){ dstoref(&p.wpart[(bP*4+chP)*2], mx); dstoref(&p.wpart[(bP*4+chP)*2+1], se); }
    }
    gbar(p.bar, ++bnum);

    // -------- P3b: mem update + read scores + chunk softmax + rv partials --------
    {
      float* bcg = ws + WS_BCG;
      float* srd = ws + WS_SRD;
      float* pRkn = ws + WS_RKN;
      float* pErs = ws + WS_ERS;
      float* pAds = ws + WS_ADS;
      float gmx = -3.4e38f, gsum = 0.f;
      #pragma unroll
      for (int cc=0; cc<4; ++cc) gmx = fmaxf(gmx, dloadf(&p.wpart[(bP*4+cc)*2]));
      #pragma unroll
      for (int cc=0; cc<4; ++cc)
        gsum += dloadf(&p.wpart[(bP*4+cc)*2+1]) * expf(dloadf(&p.wpart[(bP*4+cc)*2]) - gmx);
      float wstr = ws[WS_WSS];
      float ww = expf(ws[WS_SW + tid] - gmx)/gsum * wstr;
      unsigned* rp = mrow + tid*MS;
      float4 rr[16];
      load_row_l(rp, rr);
      #pragma unroll
      for (int i=0;i<16;++i){ int h=i*4;
        rr[i].x = rr[i].x*(1.f-ww*pErs[h  ]) + ww*pAds[h  ];
        rr[i].y = rr[i].y*(1.f-ww*pErs[h+1]) + ww*pAds[h+1];
        rr[i].z = rr[i].z*(1.f-ww*pErs[h+2]) + ww*pAds[h+2];
        rr[i].w = rr[i].w*(1.f-ww*pErs[h+3]) + ww*pAds[h+3];
      }
      store_row_l(rp, rr);
      float sum=0.f;
      #pragma unroll
      for (int i=0;i<16;++i) sum += rr[i].x+rr[i].y+rr[i].z+rr[i].w;
      float mu = sum*(1.f/64.f);
      float ssq=0.f;
      #pragma unroll
      for (int i=0;i<16;++i){ float dx=rr[i].x-mu,dy=rr[i].y-mu,dz=rr[i].z-mu,dw=rr[i].w-mu;
                              ssq+=dx*dx+dy*dy+dz*dz+dw*dw; }
      float rstd = rsqrtf(ssq*(1.f/64.f)+EPSF);
      float sN[4] = {0.f,0.f,0.f,0.f};
      #pragma unroll
      for (int i=0;i<16;++i){ int h=i*4;
        float n0=(rr[i].x-mu)*rstd*bcg[h  ]+bcg[64+h  ];
        float n1=(rr[i].y-mu)*rstd*bcg[h+1]+bcg[64+h+1];
        float n2=(rr[i].z-mu)*rstd*bcg[h+2]+bcg[64+h+2];
        float n3=(rr[i].w-mu)*rstd*bcg[h+3]+bcg[64+h+3];
        sN[0] += n0*pRkn[h    ]+n1*pRkn[h+1    ]+n2*pRkn[h+2    ]+n3*pRkn[h+3    ];
        sN[1] += n0*pRkn[64+h ]+n1*pRkn[64+h+1 ]+n2*pRkn[64+h+2 ]+n3*pRkn[64+h+3 ];
        sN[2] += n0*pRkn[128+h]+n1*pRkn[128+h+1]+n2*pRkn[128+h+2]+n3*pRkn[128+h+3];
        sN[3] += n0*pRkn[192+h]+n1*pRkn[192+h+1]+n2*pRkn[192+h+2]+n3*pRkn[192+h+3];
      }
      #pragma unroll
      for (int n=0;n<RR;++n){
        float mxn = bmax(sN[n], red);
        float sen = bsum(expf(sN[n]-mxn), red);
        srd[n*512 + tid] = expf(sN[n]-mxn);
        if (tid==0){
          dstoref(&p.rpart[(bP*4+chP)*8 + n*2], mxn);
          dstoref(&p.rpart[(bP*4+chP)*8 + n*2+1], sen);
        }
      }
      __syncthreads();
      int hs2 = (tid & 31) * 2, wg = tid >> 5;
      float a00=0,a01=0,a10=0,a11=0,a20=0,a21=0,a30=0,a31=0;
      for (int ml = wg; ml < 512; ml += 16){
        unsigned u = mrow[ml*MS + (hs2>>1)];
        float vlo = bl(u), vhi = bh(u);
        float w0 = srd[ml], w1 = srd[512+ml], w2 = srd[1024+ml], w3 = srd[1536+ml];
        a00 += w0*vlo; a01 += w0*vhi;
        a10 += w1*vlo; a11 += w1*vhi;
        a20 += w2*vlo; a21 += w2*vhi;
        a30 += w3*vlo; a31 += w3*vhi;
      }
      __syncthreads();
      float* part = ws + WS_PART;
      part[(0*16+wg)*64 + hs2] = a00; part[(0*16+wg)*64 + hs2+1] = a01;
      part[(1*16+wg)*64 + hs2] = a10; part[(1*16+wg)*64 + hs2+1] = a11;
      part[(2*16+wg)*64 + hs2] = a20; part[(2*16+wg)*64 + hs2+1] = a21;
      part[(3*16+wg)*64 + hs2] = a30; part[(3*16+wg)*64 + hs2+1] = a31;
      __syncthreads();
      if (tid < 256) {
        int n2 = tid>>6, h2 = tid&63;
        float v = 0.f;
        #pragma unroll
        for (int g2=0; g2<16; ++g2) v += part[(n2*16+g2)*64 + h2];
        dstoref(&p.rvpart[((bP*4+chP)*4 + n2)*64 + h2], v);
      }
    }
    gbar(p.bar, ++bnum);

    // -------- P4: rv combine + orow + ci (ch0) || logits(t-1) (ch1) --------
    if (chP == 0) {
      int b = bP;
      float* row   = ws + WS_ROW;
      float* cirow = ws + WS_CIROW;
      if (tid < 256) {
        int n = tid>>6, h2 = tid&63;
        float gmxn = -3.4e38f;
        #pragma unroll
        for (int cc=0; cc<4; ++cc) gmxn = fmaxf(gmxn, dloadf(&p.rpart[(b*4+cc)*8 + n*2]));
        float den=0.f, num=0.f;
        #pragma unroll
        for (int cc=0; cc<4; ++cc){
          float e = expf(dloadf(&p.rpart[(b*4+cc)*8 + n*2]) - gmxn);
          den += dloadf(&p.rpart[(b*4+cc)*8 + n*2+1]) * e;
          num += dloadf(&p.rvpart[((b*4+cc)*4 + n)*64 + h2]) * e;
        }
        row[HH + tid] = num/den;
      }
      { float* pHn = ws + WS_PHN;
        for (int i=tid;i<HH;i+=NT) row[i] = pHn[i]; }
      __syncthreads();
      float s=0.f; for (int i=tid;i<PO;i+=NT) s+=row[i];
      float mu = bsum(s,red)*(1.f/PO);
      float ss=0.f; for (int i=tid;i<PO;i+=NT){ float d=row[i]-mu; ss+=d*d; }
      float rstd = rsqrtf(bsum(ss,red)*(1.f/PO)+EPSF);
      unsigned* ob16 = p.orow16 + (size_t)(t&1)*BB*(PO/2);
      for (int i2=tid; i2<PO/2; i2+=NT){
        float v0 = (row[2*i2]-mu)*rstd*p.ln_o_g[2*i2]+p.ln_o_b[2*i2];
        float v1 = (row[2*i2+1]-mu)*rstd*p.ln_o_g[2*i2+1]+p.ln_o_b[2*i2+1];
        dstoreu(&ob16[b*(PO/2)+i2], pk2(v0, v1));
      }
      if (t+1 < LL) {
        for (int i=tid;i<CIN;i+=NT)
          cirow[i] = (i<EE)? p.x_emb[(size_t)(b*LL+t+1)*EE+i] : row[HH+(i-EE)];
        __syncthreads();
        float s2=0.f; for (int i=tid;i<CIN;i+=NT) s2+=cirow[i];
        float mu2 = bsum(s2,red)*(1.f/CIN);
        float ss2=0.f; for (int i=tid;i<CIN;i+=NT){ float d=cirow[i]-mu2; ss2+=d*d; }
        float rstd2 = rsqrtf(bsum(ss2,red)*(1.f/CIN)+EPSF);
        for (int i2=tid; i2<CIN/2; i2+=NT){
          float v0 = (cirow[2*i2]-mu2)*rstd2*p.ln_in_g[2*i2]+p.ln_in_b[2*i2];
          float v1 = (cirow[2*i2+1]-mu2)*rstd2*p.ln_in_g[2*i2+1]+p.ln_in_b[2*i2+1];
          dstoreu(&p.ci16[b*(CIN/2)+i2], pk2(v0, v1));
        }
      }
    } else if (chP == 1 && t > 0) {
      logits_tile(p, wlog, tid, t-1, ws);
    }
    gbar(p.bar, ++bnum);
  }

  // ---------------- finale: LDS mem -> fp32 memT + logits(255) ----------------
  {
    float* dst = p.mem + ((size_t)bP*MM + chP*CSL)*HSZ;
    int ml = tid;
    const uint4* src = (const uint4*)(mrow + ml*MS);
    float4* d4 = (float4*)(dst + (size_t)ml*HSZ);
    #pragma unroll
    for (int j=0;j<8;++j){
      uint4 q = src[j];
      d4[2*j]   = make_float4(bl(q.x),bh(q.x),bl(q.y),bh(q.y));
      d4[2*j+1] = make_float4(bl(q.z),bh(q.z),bl(q.w),bh(q.w));
    }
  }
  if (chP == 1) logits_tile(p, wlog, tid, LL-1, ws);
}

extern "C" void kernel_launch(void* const* d_in, const int* in_sizes, int n_in,
                              void* d_out, int out_size, void* d_ws, size_t ws_size,
                              hipStream_t stream) {
  Params prm;
  prm.x_emb  = (const float*)d_in[0];
  prm.ln_in_g= (const float*)d_in[1];
  prm.ln_in_b= (const float*)d_in[2];
  prm.w_ih   = (const float*)d_in[3];
  prm.w_hh   = (const float*)d_in[4];
  prm.b_ih   = (const float*)d_in[5];
  prm.b_hh   = (const float*)d_in[6];
  prm.ln_c_g = (const float*)d_in[7];
  prm.ln_c_b = (const float*)d_in[8];
  prm.w_rk   = (const float*)d_in[9];
  prm.b_rk   = (const float*)d_in[10];
  prm.w_wk   = (const float*)d_in[11];
  prm.b_wk   = (const float*)d_in[12];
  prm.w_ws   = (const float*)d_in[13];
  prm.b_ws   = (const float*)d_in[14];
  prm.w_er   = (const float*)d_in[15];
  prm.b_er   = (const float*)d_in[16];
  prm.w_ad   = (const float*)d_in[17];
  prm.b_ad   = (const float*)d_in[18];
  prm.ln_rk_g= (const float*)d_in[19];
  prm.ln_rk_b= (const float*)d_in[20];
  prm.ln_wk_g= (const float*)d_in[21];
  prm.ln_wk_b= (const float*)d_in[22];
  prm.ln_m_g = (const float*)d_in[23];
  prm.ln_m_b = (const float*)d_in[24];
  prm.ln_o_g = (const float*)d_in[25];
  prm.ln_o_b = (const float*)d_in[26];
  prm.w_p    = (const float*)d_in[27];
  prm.b_p    = (const float*)d_in[28];

  float* out = (float*)d_out;
  prm.y   = out + OUT_Y;
  prm.mem = out + OUT_MEM;
  prm.ht  = out + OUT_HT;
  prm.ct  = out + OUT_CT;

  prm.bar = (unsigned*)d_ws;
  hipMemsetAsync(d_ws, 0, 4096, stream);

  float* ws = (float*)((char*)d_ws + 4096);
  size_t o = 0;
  prm.c      = ws + o; o += BB*HH;
  prm.h16    = (unsigned*)(ws + o); o += BB*HH;
  prm.ci16   = (unsigned*)(ws + o); o += (BB*CIN)/2;
  prm.orow16 = (unsigned*)(ws + o); o += BB*PO;
  prm.wpart  = ws + o; o += 256*2;
  prm.rpart  = ws + o; o += 256*8;
  prm.rvpart = ws + o; o += 256*4*64;
  prm.rawbuf = ws + o; o += BB*452;
  prm.wih16  = (unsigned short*)(ws + o); o += (4096*CIN)/2;
  prm.whh16  = (unsigned short*)(ws + o); o += (4096*HH)/2;
  prm.wp16   = (unsigned short*)(ws + o); o += (OO*PO)/2;
  prm.whd16  = (unsigned short*)(ws + o); o += (449*HH)/2 + 64;

  hipFuncSetAttribute((const void*)dnc_all,
                      hipFuncAttributeMaxDynamicSharedMemorySize, DYN_BYTES);

  dnc_all<<<dim3(NB_REQ), dim3(NT), DYN_BYTES, stream>>>(prm);
}